// Round 3
// baseline (1671.499 us; speedup 1.0000x reference)
//
#include <hip/hip_runtime.h>
#include <math.h>

#define BATCH 16
#define SRCLEN 128
#define DIM 512
#define VOCABSZ 32000
#define BEAM 4
#define MAXLEN 16
#define NROWS (BATCH*BEAM)   // 64
#define BOS_TOK 1
#define EOS_TOK 2
#define NEGINF 1e9f
#define CHUNKS 8
#define CHUNK 4000           // VOCABSZ / CHUNKS
#define PCH 8                // pool s-chunks
#define PCL (SRCLEN/PCH)     // 16 s per chunk

// ---------------- key pack/unpack: (ordered float << 32) | (0xFFFFFFFF - id) ----------------
__device__ inline unsigned long long packkey(float v, int idx) {
    unsigned int fb = __float_as_uint(v);
    fb = fb ^ ((fb >> 31) ? 0xFFFFFFFFu : 0x80000000u);
    return ((unsigned long long)fb << 32) | (unsigned long long)(0xFFFFFFFFu - (unsigned int)idx);
}
__device__ inline float unpack_val(unsigned long long k) {
    unsigned int fb = (unsigned int)(k >> 32);
    fb = fb ^ ((fb >> 31) ? 0x80000000u : 0xFFFFFFFFu);
    return __uint_as_float(fb);
}
__device__ inline int unpack_id(unsigned long long k) {
    return (int)(0xFFFFFFFFu - (unsigned int)(k & 0xFFFFFFFFu));
}
__device__ inline unsigned long long shflxor64(unsigned long long x, int mask) {
    unsigned int lo = (unsigned int)x, hi = (unsigned int)(x >> 32);
    lo = (unsigned int)__shfl_xor((int)lo, mask, 64);
    hi = (unsigned int)__shfl_xor((int)hi, mask, 64);
    return ((unsigned long long)hi << 32) | (unsigned long long)lo;
}
__device__ inline unsigned long long wavemax64(unsigned long long k) {
#pragma unroll
    for (int off = 1; off < 64; off <<= 1) {
        unsigned long long o = shflxor64(k, off);
        k = (o > k) ? o : k;
    }
    return k;
}

// ---------------- encoder pool, phase 1: per-(b, s-chunk) partial sum + count ----------------
__global__ __launch_bounds__(512) void k_pool2(const int* __restrict__ src,
                                               const float* __restrict__ Esrc,
                                               float* __restrict__ pp, float* __restrict__ pcnt) {
    int b = blockIdx.x, c = blockIdx.y;
    int d = threadIdx.x;
    float acc = 0.f, cnt = 0.f;
#pragma unroll
    for (int s = 0; s < PCL; ++s) {
        int tok = src[b * SRCLEN + c * PCL + s];
        if (tok != 0) { acc += Esrc[(size_t)tok * DIM + d]; cnt += 1.f; }
    }
    pp[(b * PCH + c) * DIM + d] = acc;
    if (d == 0) pcnt[b * PCH + c] = cnt;
}

// ---------------- encoder pool, phase 2: reduce chunks (ascending, deterministic) ----------------
__global__ __launch_bounds__(512) void k_poolred(const float* __restrict__ pp,
                                                 const float* __restrict__ pcnt,
                                                 float* __restrict__ pooled) {
    int b = blockIdx.x;
    int d = threadIdx.x;
    float acc = 0.f, cnt = 0.f;
#pragma unroll
    for (int c = 0; c < PCH; ++c) { acc += pp[(b * PCH + c) * DIM + d]; cnt += pcnt[b * PCH + c]; }
    pooled[b * DIM + d] = acc / fmaxf(cnt, 1.f);
}

// ---------------- state init ----------------
__global__ __launch_bounds__(1024) void k_init(int* __restrict__ alive_seq, float* __restrict__ alive_lp,
                                               int* __restrict__ fin_seq, float* __restrict__ fin_scores,
                                               int* __restrict__ fin_flags, int* __restrict__ batch_fin) {
    int tid = threadIdx.x;  // 1024 = NROWS*MAXLEN
    alive_seq[tid] = (tid % MAXLEN == 0) ? BOS_TOK : 0;
    fin_seq[tid] = 0;
    if (tid < NROWS) {
        alive_lp[tid] = (tid % BEAM == 0) ? 0.f : -INFINITY;
        fin_scores[tid] = -NEGINF;
        fin_flags[tid] = 0;
    }
    if (tid < BATCH) batch_fin[tid] = 0;
}

// ---------------- decoder input, transposed: xT[d][i] = E_tgt[last_i][d] + pooled[i/4][d] ----------------
__global__ __launch_bounds__(512) void k_x(const float* __restrict__ Etgt,
                                           const float* __restrict__ pooled,
                                           const int* __restrict__ alive_seq, int t,
                                           float* __restrict__ xT) {
    int i = blockIdx.x;   // row 0..63
    int d = threadIdx.x;  // 0..511
    int last = alive_seq[i * MAXLEN + t];
    float v = Etgt[(size_t)last * DIM + d] + pooled[(i >> 2) * DIM + d];
    xT[d * NROWS + i] = v;
}

// ---------------- logits GEMM: 4 rows x 4 vocab register tile per lane ----------------
// R8 post-mortem: R7's 16-row/1-vocab layout needed 64 x-floats per 4-d iter
// as scalar loads (4 fma per s_load); conservative lgkmcnt(0) serialization ->
// VALUBusy 28%, 55us. Now: lane = 4 rows x 4 vocab outer product. Per d-step:
// 1 W float4 (lanes contiguous -> 1KB/instr), 1 uniform x float4 (broadcast,
// feeds 16 fma), 16 fma => ~80% fma issue fraction. Grid 125 vtiles x 16
// rowgroups = 2000 single-wave blocks (~2/SIMD). No split-K: K=512 in one
// pass, partial slab 8MB (was 32), k_part reads 1 slab.
// d-ascending accumulation: same reassociation class as accepted before.
__global__ __launch_bounds__(64) void k_gemm5(const float* __restrict__ xT,
                                              const float* __restrict__ W,
                                              float* __restrict__ partial) {
    int lane = threadIdx.x;                 // 0..63
    int v0 = blockIdx.x * 256 + lane * 4;   // vocab quad
    int r0 = blockIdx.y * 4;                // row quad (wave-uniform)
    float4 a0 = {0.f,0.f,0.f,0.f}, a1 = a0, a2 = a0, a3 = a0;
    const float* wp = W + v0;
    const float* xp = xT + r0;
#define STEP(xv, wv) \
    a0.x = fmaf(xv.x, wv.x, a0.x); a0.y = fmaf(xv.x, wv.y, a0.y); \
    a0.z = fmaf(xv.x, wv.z, a0.z); a0.w = fmaf(xv.x, wv.w, a0.w); \
    a1.x = fmaf(xv.y, wv.x, a1.x); a1.y = fmaf(xv.y, wv.y, a1.y); \
    a1.z = fmaf(xv.y, wv.z, a1.z); a1.w = fmaf(xv.y, wv.w, a1.w); \
    a2.x = fmaf(xv.z, wv.x, a2.x); a2.y = fmaf(xv.z, wv.y, a2.y); \
    a2.z = fmaf(xv.z, wv.z, a2.z); a2.w = fmaf(xv.z, wv.w, a2.w); \
    a3.x = fmaf(xv.w, wv.x, a3.x); a3.y = fmaf(xv.w, wv.y, a3.y); \
    a3.z = fmaf(xv.w, wv.z, a3.z); a3.w = fmaf(xv.w, wv.w, a3.w);
#pragma unroll 2
    for (int d = 0; d < DIM; d += 4) {
        float4 w0 = *(const float4*)(wp);
        float4 w1 = *(const float4*)(wp + (size_t)VOCABSZ);
        float4 w2 = *(const float4*)(wp + (size_t)2 * VOCABSZ);
        float4 w3 = *(const float4*)(wp + (size_t)3 * VOCABSZ);
        wp += (size_t)4 * VOCABSZ;
        float4 x0 = *(const float4*)(xp);
        float4 x1 = *(const float4*)(xp + NROWS);
        float4 x2 = *(const float4*)(xp + 2 * NROWS);
        float4 x3 = *(const float4*)(xp + 3 * NROWS);
        xp += 4 * NROWS;
        STEP(x0, w0)
        STEP(x1, w1)
        STEP(x2, w2)
        STEP(x3, w3)
    }
#undef STEP
    float* op = partial + (size_t)r0 * VOCABSZ + v0;
    *(float4*)(op) = a0;
    *(float4*)(op + (size_t)VOCABSZ) = a1;
    *(float4*)(op + (size_t)2 * VOCABSZ) = a2;
    *(float4*)(op + (size_t)3 * VOCABSZ) = a3;
}

// ---------------- per-(row,chunk): partial max, sumexp, top-8 ----------------
// R8: 1024 threads (32 waves/CU), 1 float4/slab per thread (all loads
// independent/in-flight), 4-barrier merge: sort-4 network -> per-wave top-8
// via shfl wave-max rounds -> 128 keys in LDS -> wave0 extracts block top-8.
template<int NZ>
__global__ __launch_bounds__(1024) void k_part(const float* __restrict__ partial,
                                               const float* __restrict__ bias,
                                               float* __restrict__ pm, float* __restrict__ ps,
                                               float* __restrict__ ptopv, int* __restrict__ ptopi) {
    int row = blockIdx.x, ch = blockIdx.y;
    int tid = threadIdx.x;
    int lane = tid & 63;
    int wv = tid >> 6;                    // 0..15
    const size_t slab = (size_t)NROWS * VOCABSZ;
    const bool valid = tid < (CHUNK / 4); // 1000 float4 positions

    float vals[4] = {-INFINITY, -INFINITY, -INFINITY, -INFINITY};
    if (valid) {
        const float4* l0 = (const float4*)(partial + (size_t)row * VOCABSZ + ch * CHUNK);
        float4 q = l0[tid];
#pragma unroll
        for (int zz = 1; zz < NZ; ++zz) {
            const float4* lz = (const float4*)(partial + slab * zz + (size_t)row * VOCABSZ + ch * CHUNK);
            float4 q2 = lz[tid];
            q.x += q2.x; q.y += q2.y; q.z += q2.z; q.w += q2.w;
        }
        float4 bb = ((const float4*)(bias + ch * CHUNK))[tid];
        vals[0] = q.x + bb.x; vals[1] = q.y + bb.y; vals[2] = q.z + bb.z; vals[3] = q.w + bb.w;
    }

    // ---- block max: wave butterfly + 16-entry LDS combine ----
    float m_t = fmaxf(fmaxf(vals[0], vals[1]), fmaxf(vals[2], vals[3]));
#pragma unroll
    for (int off = 1; off < 64; off <<= 1) m_t = fmaxf(m_t, __shfl_xor(m_t, off, 64));
    __shared__ float swred[16];
    if (lane == 0) swred[wv] = m_t;
    __syncthreads();
    float m = swred[0];
#pragma unroll
    for (int w = 1; w < 16; ++w) m = fmaxf(m, swred[w]);
    __syncthreads();   // swred reused for sums below

    // ---- block sumexp ----
    float se = 0.f;
    if (valid) {
#pragma unroll
        for (int c = 0; c < 4; ++c) se += expf(vals[c] - m);
    }
#pragma unroll
    for (int off = 1; off < 64; off <<= 1) se += __shfl_xor(se, off, 64);
    if (lane == 0) swred[wv] = se;
    __syncthreads();
    if (tid == 0) {
        float s = 0.f;
#pragma unroll
        for (int w = 0; w < 16; ++w) s += swred[w];
        pm[row * CHUNKS + ch] = m;
        ps[row * CHUNKS + ch] = s;
    }

    // ---- top-8: per-lane sort-4 -> per-wave 8 rounds wave-max -> 128-key final ----
    int gi = ch * CHUNK + tid * 4;
    unsigned long long k0 = 0ULL, k1 = 0ULL, k2 = 0ULL, k3 = 0ULL;
    if (valid) {   // keys never 0 for real values (idx < 2^31) -> 0 is a safe sentinel
        k0 = packkey(vals[0], gi);
        k1 = packkey(vals[1], gi + 1);
        k2 = packkey(vals[2], gi + 2);
        k3 = packkey(vals[3], gi + 3);
    }
    {
        unsigned long long tswp;
#define CSW(a,b) if (b > a) { tswp = a; a = b; b = tswp; }
        CSW(k0,k1) CSW(k2,k3) CSW(k0,k2) CSW(k1,k3) CSW(k1,k2)
#undef CSW
    }
    __shared__ unsigned long long skey[128];
    {
        int pos = 0;
        unsigned long long wtop[8];
#pragma unroll
        for (int r = 0; r < 8; ++r) {
            unsigned long long head = (pos == 0) ? k0 : (pos == 1) ? k1 :
                                      (pos == 2) ? k2 : (pos == 3) ? k3 : 0ULL;
            unsigned long long mx = wavemax64(head);
            if (head == mx && head != 0ULL) pos++;   // unique keys -> exactly one winner
            wtop[r] = mx;
        }
        if (lane == 0) {
#pragma unroll
            for (int r = 0; r < 8; ++r) skey[wv * 8 + r] = wtop[r];
        }
    }
    __syncthreads();
    if (tid < 64) {   // wave 0 exactly; no barriers below
        unsigned long long a = skey[tid];
        unsigned long long b2 = skey[64 + tid];
        unsigned long long hi = (a > b2) ? a : b2;
        unsigned long long lo = (a > b2) ? b2 : a;
        float* otv = ptopv + ((size_t)row * CHUNKS + ch) * 8;
        int*   oti = ptopi + ((size_t)row * CHUNKS + ch) * 8;
        int pos = 0;
#pragma unroll
        for (int r = 0; r < 8; ++r) {
            unsigned long long head = (pos == 0) ? hi : (pos == 1) ? lo : 0ULL;
            unsigned long long mx = wavemax64(head);
            if (head == mx && head != 0ULL) pos++;
            if (tid == 0) { otv[r] = unpack_val(mx); oti[r] = unpack_id(mx); }
        }
    }
}

// ---------------- merge + beam bookkeeping, one block (one wave) per batch ----------------
__global__ __launch_bounds__(64) void k_mergesel(const float* __restrict__ pm, const float* __restrict__ ps,
                                                 const float* __restrict__ ptopv, const int* __restrict__ ptopi,
                                                 int* __restrict__ alive_seq, float* __restrict__ alive_lp,
                                                 int* __restrict__ fin_seq, float* __restrict__ fin_scores,
                                                 int* __restrict__ fin_flags, int* __restrict__ batch_fin, int t) {
    int b = blockIdx.x;
    int tid = threadIdx.x;
    __shared__ int aseq_old[BEAM][MAXLEN]; __shared__ int fseq_old[BEAM][MAXLEN];
    __shared__ float s_tlp[8]; __shared__ int s_ttok[8], s_tbeam[8];
    __shared__ int s_aidx[4], s_fidx[4];
    __shared__ float s_nfsc[4]; __shared__ int s_nffl[4];
    float lpen = (float)(t + 1);

    { int k = tid >> 4, p = tid & 15;
      aseq_old[k][p] = alive_seq[(b * BEAM + k) * MAXLEN + p];
      fseq_old[k][p] = fin_seq[(b * BEAM + k) * MAXLEN + p]; }

    float rv[4]; int ri[4];
#pragma unroll
    for (int k = 0; k < 4; ++k) {
        rv[k] = ptopv[(size_t)(b * BEAM + k) * 64 + tid];
        ri[k] = ptopi[(size_t)(b * BEAM + k) * 64 + tid];
    }

    float alp[4], fsc[4]; int ffl[4];
#pragma unroll
    for (int k = 0; k < 4; ++k) {
        alp[k] = alive_lp[b * BEAM + k];
        fsc[k] = fin_scores[b * BEAM + k];
        ffl[k] = fin_flags[b * BEAM + k];
    }
    int bf_old = batch_fin[b];

    float srm[4], srl[4];
#pragma unroll
    for (int k = 0; k < 4; ++k) {
        float m = -INFINITY;
#pragma unroll
        for (int c = 0; c < CHUNKS; ++c) m = fmaxf(m, pm[(b * BEAM + k) * CHUNKS + c]);
        float s = 0.f;
#pragma unroll
        for (int c = 0; c < CHUNKS; ++c) s += ps[(b * BEAM + k) * CHUNKS + c] * expf(pm[(b * BEAM + k) * CHUNKS + c] - m);
        srm[k] = m; srl[k] = logf(s);
    }

    unsigned long long key[4];
#pragma unroll
    for (int k = 0; k < 4; ++k) {
        float sh = rv[k] - srm[k];
        float lp = sh - srl[k];
        float full = alp[k] + lp;
        float cv = full / lpen;
        key[k] = packkey(cv, k * VOCABSZ + ri[k]);
    }
    {
        unsigned long long tmp;
#define CSW(a,b) if (key[b] > key[a]) { tmp = key[a]; key[a] = key[b]; key[b] = tmp; }
        CSW(0,1) CSW(2,3) CSW(0,2) CSW(1,3) CSW(1,2)
#undef CSW
    }

    float tscore[8], tlp[8]; int ttok[8], tbeam[8], tfin[8];
    int pos = 0;
#pragma unroll
    for (int r = 0; r < 8; ++r) {
        unsigned long long head = (pos == 0) ? key[0] : (pos == 1) ? key[1] :
                                  (pos == 2) ? key[2] : (pos == 3) ? key[3] : 0ULL;
        unsigned long long mx = wavemax64(head);
        if (head == mx && head != 0ULL) pos++;
        float sc = unpack_val(mx);
        int id = unpack_id(mx);
        tscore[r] = sc;
        tlp[r] = sc * lpen;
        ttok[r] = id % VOCABSZ;
        tbeam[r] = id / VOCABSZ;
        tfin[r] = (ttok[r] == EOS_TOK) ? 1 : 0;
    }

    int aidx[4];
    {
        float curr[8];
#pragma unroll
        for (int j = 0; j < 8; ++j) curr[j] = tscore[j] + (tfin[j] ? -NEGINF : 0.0f);
        unsigned int used = 0;
#pragma unroll
        for (int r = 0; r < 4; ++r) {
            float bv = 0.f; int bj = -1;
#pragma unroll
            for (int j = 0; j < 8; ++j) {
                bool skip = (used >> j) & 1u;
                bool better = !skip && (bj < 0 || curr[j] > bv);
                if (better) { bv = curr[j]; bj = j; }
            }
            used |= 1u << bj; aidx[r] = bj;
        }
    }
    int fidx[4]; float nfsc[4]; int nffl[4];
    {
        float fscand[12]; int fflcand[12];
#pragma unroll
        for (int j = 0; j < 4; ++j) { fscand[j] = fsc[j]; fflcand[j] = ffl[j]; }
#pragma unroll
        for (int q = 0; q < 8; ++q) {
            float t1 = tscore[q] + (tfin[q] ? 0.0f : -NEGINF);
            float t2 = t1 + (bf_old ? -NEGINF : 0.0f);
            fscand[4 + q] = t2; fflcand[4 + q] = tfin[q];
        }
        unsigned int used = 0;
#pragma unroll
        for (int r = 0; r < 4; ++r) {
            float bv = 0.f; int bj = -1;
#pragma unroll
            for (int j = 0; j < 12; ++j) {
                bool skip = (used >> j) & 1u;
                bool better = !skip && (bj < 0 || fscand[j] > bv);
                if (better) { bv = fscand[j]; bj = j; }
            }
            used |= 1u << bj; fidx[r] = bj;
            nfsc[r] = bv;
        }
#pragma unroll
        for (int r = 0; r < 4; ++r) {
            int bj = fidx[r]; int fl = 0;
#pragma unroll
            for (int j = 0; j < 12; ++j) if (bj == j) fl = fflcand[j];
            nffl[r] = fl;
        }
    }

    if (tid == 0) {
#pragma unroll
        for (int r = 0; r < 8; ++r) { s_tlp[r] = tlp[r]; s_ttok[r] = ttok[r]; s_tbeam[r] = tbeam[r]; }
#pragma unroll
        for (int r = 0; r < 4; ++r) { s_aidx[r] = aidx[r]; s_fidx[r] = fidx[r]; s_nfsc[r] = nfsc[r]; s_nffl[r] = nffl[r]; }
    }
    __syncthreads();

    { int k = tid >> 4, p = tid & 15;
      int j = s_aidx[k];
      int val = (p == t + 1) ? s_ttok[j] : aseq_old[s_tbeam[j]][p];
      alive_seq[(b * BEAM + k) * MAXLEN + p] = val;
      int fi = s_fidx[k]; int fval;
      if (fi < 4) fval = fseq_old[fi][p];
      else { int q = fi - 4; fval = (p == t + 1) ? s_ttok[q] : aseq_old[s_tbeam[q]][p]; }
      fin_seq[(b * BEAM + k) * MAXLEN + p] = fval; }

    if (tid < 4) {
        alive_lp[b * BEAM + tid] = s_tlp[s_aidx[tid]];
        fin_scores[b * BEAM + tid] = s_nfsc[tid];
        fin_flags[b * BEAM + tid] = s_nffl[tid];
    }
    if (tid == 0) {
        float lb = s_tlp[s_aidx[0]] / lpen;
        float lowest = nfsc[0] * (nffl[0] ? 1.f : 0.f);
        int allf = nffl[0];
#pragma unroll
        for (int k2 = 1; k2 < 4; ++k2) {
            float pz = nfsc[k2] * (nffl[k2] ? 1.f : 0.f);
            lowest = fminf(lowest, pz);
            allf = allf && nffl[k2];
        }
        lowest = lowest + (allf ? 0.f : -NEGINF);
        batch_fin[b] = bf_old || (lowest >= lb);
    }
}

// ---------------- output: fin_seq[:,0,:] as float ----------------
__global__ __launch_bounds__(256) void k_out(const int* __restrict__ fin_seq, float* __restrict__ out) {
    int tid = threadIdx.x;
    if (tid < BATCH * MAXLEN) {
        int b = tid / MAXLEN, p = tid % MAXLEN;
        out[tid] = (float)fin_seq[(b * BEAM + 0) * MAXLEN + p];
    }
}

extern "C" void kernel_launch(void* const* d_in, const int* in_sizes, int n_in,
                              void* d_out, int out_size, void* d_ws, size_t ws_size,
                              hipStream_t stream) {
    const int*   src  = (const int*)d_in[0];
    const float* Esrc = (const float*)d_in[1];
    const float* Etgt = (const float*)d_in[2];
    const float* W    = (const float*)d_in[3];
    const float* bias = (const float*)d_in[4];
    float* out = (float*)d_out;

    const size_t slab = (size_t)NROWS * VOCABSZ * 4;  // 8.192 MB (single slab, no split-K)

    char* p = (char*)d_ws;
    float* partial    = (float*)p; p += slab;
    float* pooled     = (float*)p; p += BATCH * DIM * 4;
    float* xT         = (float*)p; p += DIM * NROWS * 4;
    float* pp         = (float*)p; p += BATCH * PCH * DIM * 4;   // 256 KB
    float* pcnt       = (float*)p; p += BATCH * PCH * 4;
    float* pm         = (float*)p; p += NROWS * CHUNKS * 4;
    float* ps         = (float*)p; p += NROWS * CHUNKS * 4;
    float* ptopv      = (float*)p; p += NROWS * CHUNKS * 8 * 4;
    int*   ptopi      = (int*)p;   p += NROWS * CHUNKS * 8 * 4;
    int*   alive_seq  = (int*)p;   p += NROWS * MAXLEN * 4;
    int*   fin_seq    = (int*)p;   p += NROWS * MAXLEN * 4;
    float* alive_lp   = (float*)p; p += NROWS * 4;
    float* fin_scores = (float*)p; p += NROWS * 4;
    int*   fin_flags  = (int*)p;   p += NROWS * 4;
    int*   batch_fin  = (int*)p;   p += BATCH * 4;

    k_pool2<<<dim3(BATCH, PCH), DIM, 0, stream>>>(src, Esrc, pp, pcnt);
    k_poolred<<<BATCH, DIM, 0, stream>>>(pp, pcnt, pooled);
    k_init<<<1, 1024, 0, stream>>>(alive_seq, alive_lp, fin_seq, fin_scores, fin_flags, batch_fin);
    for (int t = 0; t < MAXLEN - 1; ++t) {
        k_x<<<NROWS, DIM, 0, stream>>>(Etgt, pooled, alive_seq, t, xT);
        k_gemm5<<<dim3(VOCABSZ / 256, NROWS / 4), 64, 0, stream>>>(xT, W, partial);
        k_part<1><<<dim3(NROWS, CHUNKS), 1024, 0, stream>>>(partial, bias, pm, ps, ptopv, ptopi);
        k_mergesel<<<BATCH, 64, 0, stream>>>(pm, ps, ptopv, ptopi, alive_seq, alive_lp,
                                             fin_seq, fin_scores, fin_flags, batch_fin, t);
    }
    k_out<<<1, 256, 0, stream>>>(fin_seq, out);
}

// Round 4
// 1231.968 us; speedup vs baseline: 1.3568x; 1.3568x over previous
//
#include <hip/hip_runtime.h>
#include <math.h>

#define BATCH 16
#define SRCLEN 128
#define DIM 512
#define VOCABSZ 32000
#define BEAM 4
#define MAXLEN 16
#define NROWS (BATCH*BEAM)   // 64
#define BOS_TOK 1
#define EOS_TOK 2
#define NEGINF 1e9f
#define CHUNKS 8
#define CHUNK 4000           // VOCABSZ / CHUNKS
#define PCH 8                // pool s-chunks
#define PCL (SRCLEN/PCH)     // 16 s per chunk
#define GD 256               // gemm d-slab (DIM/2)

// ---------------- key pack/unpack: (ordered float << 32) | (0xFFFFFFFF - id) ----------------
__device__ inline unsigned long long packkey(float v, int idx) {
    unsigned int fb = __float_as_uint(v);
    fb = fb ^ ((fb >> 31) ? 0xFFFFFFFFu : 0x80000000u);
    return ((unsigned long long)fb << 32) | (unsigned long long)(0xFFFFFFFFu - (unsigned int)idx);
}
__device__ inline float unpack_val(unsigned long long k) {
    unsigned int fb = (unsigned int)(k >> 32);
    fb = fb ^ ((fb >> 31) ? 0x80000000u : 0xFFFFFFFFu);
    return __uint_as_float(fb);
}
__device__ inline int unpack_id(unsigned long long k) {
    return (int)(0xFFFFFFFFu - (unsigned int)(k & 0xFFFFFFFFu));
}
__device__ inline unsigned long long shflxor64(unsigned long long x, int mask) {
    unsigned int lo = (unsigned int)x, hi = (unsigned int)(x >> 32);
    lo = (unsigned int)__shfl_xor((int)lo, mask, 64);
    hi = (unsigned int)__shfl_xor((int)hi, mask, 64);
    return ((unsigned long long)hi << 32) | (unsigned long long)lo;
}
__device__ inline unsigned long long wavemax64(unsigned long long k) {
#pragma unroll
    for (int off = 1; off < 64; off <<= 1) {
        unsigned long long o = shflxor64(k, off);
        k = (o > k) ? o : k;
    }
    return k;
}

// ---------------- encoder pool, phase 1: per-(b, s-chunk) partial sum + count ----------------
__global__ __launch_bounds__(512) void k_pool2(const int* __restrict__ src,
                                               const float* __restrict__ Esrc,
                                               float* __restrict__ pp, float* __restrict__ pcnt) {
    int b = blockIdx.x, c = blockIdx.y;
    int d = threadIdx.x;
    float acc = 0.f, cnt = 0.f;
#pragma unroll
    for (int s = 0; s < PCL; ++s) {
        int tok = src[b * SRCLEN + c * PCL + s];
        if (tok != 0) { acc += Esrc[(size_t)tok * DIM + d]; cnt += 1.f; }
    }
    pp[(b * PCH + c) * DIM + d] = acc;
    if (d == 0) pcnt[b * PCH + c] = cnt;
}

// ---------------- encoder pool, phase 2: reduce chunks (ascending, deterministic) ----------------
__global__ __launch_bounds__(512) void k_poolred(const float* __restrict__ pp,
                                                 const float* __restrict__ pcnt,
                                                 float* __restrict__ pooled) {
    int b = blockIdx.x;
    int d = threadIdx.x;
    float acc = 0.f, cnt = 0.f;
#pragma unroll
    for (int c = 0; c < PCH; ++c) { acc += pp[(b * PCH + c) * DIM + d]; cnt += pcnt[b * PCH + c]; }
    pooled[b * DIM + d] = acc / fmaxf(cnt, 1.f);
}

// ---------------- state init ----------------
__global__ __launch_bounds__(1024) void k_init(int* __restrict__ alive_seq, float* __restrict__ alive_lp,
                                               int* __restrict__ fin_seq, float* __restrict__ fin_scores,
                                               int* __restrict__ fin_flags, int* __restrict__ batch_fin) {
    int tid = threadIdx.x;  // 1024 = NROWS*MAXLEN
    alive_seq[tid] = (tid % MAXLEN == 0) ? BOS_TOK : 0;
    fin_seq[tid] = 0;
    if (tid < NROWS) {
        alive_lp[tid] = (tid % BEAM == 0) ? 0.f : -INFINITY;
        fin_scores[tid] = -NEGINF;
        fin_flags[tid] = 0;
    }
    if (tid < BATCH) batch_fin[tid] = 0;
}

// ---------------- decoder input, transposed: xT[d][i] = E_tgt[last_i][d] + pooled[i/4][d] ----------------
__global__ __launch_bounds__(512) void k_x(const float* __restrict__ Etgt,
                                           const float* __restrict__ pooled,
                                           const int* __restrict__ alive_seq, int t,
                                           float* __restrict__ xT) {
    int i = blockIdx.x;   // row 0..63
    int d = threadIdx.x;  // 0..511
    int last = alive_seq[i * MAXLEN + t];
    float v = Etgt[(size_t)last * DIM + d] + pooled[(i >> 2) * DIM + d];
    xT[d * NROWS + i] = v;
}

// ---------------- logits GEMM: block = 256 vocab x ALL 64 rows, x staged in LDS ----------------
// R9 post-mortem of R8 (k_gemm5): 16 row-group blocks each demanded the whole
// W -> 16x demand, FETCH 257MB (4x W after cache absorption), 82us fetch-bound.
// Now each W element is read by exactly ONE block (W demand = 1x = 65.5MB per
// dispatch; L3-residency across steps possible). 16 waves x 4 rows = 64 rows
// per block; lane = 4 rows x 4 vocab (R8's dense 16-fma-per-W-float4 issue).
// x tile (256d x 64r = 64KB) staged in LDS once; in-loop x reads are
// wave-uniform ds_read (broadcast, conflict-free) -> no R7 scalar-load
// serialization. d split z=2 (256 d each) -> 250 blocks ~ 1/CU.
// Per-slab d-ascending accumulation; k_part<2> sums slabs (same split-K
// semantics verified at NZ=4 in R7 and NZ=1 in R8, absmax 0 both).
__global__ __launch_bounds__(1024) void k_gemm6(const float* __restrict__ xT,
                                                const float* __restrict__ W,
                                                float* __restrict__ partial) {
    int lane = threadIdx.x & 63;
    int wv   = threadIdx.x >> 6;            // 0..15
    int v0 = blockIdx.x * 256 + lane * 4;   // vocab quad
    int r0 = wv * 4;                        // row quad (wave-uniform)
    int z  = blockIdx.z;
    int d0 = z * GD;

    __shared__ float xs[GD * NROWS];        // 64 KB
    {
        const float4* xg = (const float4*)(xT + (size_t)d0 * NROWS);
        float4* xs4 = (float4*)xs;
#pragma unroll
        for (int i = 0; i < (GD * NROWS / 4) / 1024; ++i)
            xs4[i * 1024 + threadIdx.x] = xg[i * 1024 + threadIdx.x];
    }
    __syncthreads();

    float4 a0 = {0.f,0.f,0.f,0.f}, a1 = a0, a2 = a0, a3 = a0;
    const float* wp = W + (size_t)d0 * VOCABSZ + v0;
    const float* xp = xs + r0;
#define STEP(xv, wv_) \
    a0.x = fmaf(xv.x, wv_.x, a0.x); a0.y = fmaf(xv.x, wv_.y, a0.y); \
    a0.z = fmaf(xv.x, wv_.z, a0.z); a0.w = fmaf(xv.x, wv_.w, a0.w); \
    a1.x = fmaf(xv.y, wv_.x, a1.x); a1.y = fmaf(xv.y, wv_.y, a1.y); \
    a1.z = fmaf(xv.y, wv_.z, a1.z); a1.w = fmaf(xv.y, wv_.w, a1.w); \
    a2.x = fmaf(xv.z, wv_.x, a2.x); a2.y = fmaf(xv.z, wv_.y, a2.y); \
    a2.z = fmaf(xv.z, wv_.z, a2.z); a2.w = fmaf(xv.z, wv_.w, a2.w); \
    a3.x = fmaf(xv.w, wv_.x, a3.x); a3.y = fmaf(xv.w, wv_.y, a3.y); \
    a3.z = fmaf(xv.w, wv_.z, a3.z); a3.w = fmaf(xv.w, wv_.w, a3.w);
#pragma unroll 2
    for (int d = 0; d < GD; d += 4) {
        float4 w0 = *(const float4*)(wp);
        float4 w1 = *(const float4*)(wp + (size_t)VOCABSZ);
        float4 w2 = *(const float4*)(wp + (size_t)2 * VOCABSZ);
        float4 w3 = *(const float4*)(wp + (size_t)3 * VOCABSZ);
        wp += (size_t)4 * VOCABSZ;
        float4 x0 = *(const float4*)(xp);
        float4 x1 = *(const float4*)(xp + NROWS);
        float4 x2 = *(const float4*)(xp + 2 * NROWS);
        float4 x3 = *(const float4*)(xp + 3 * NROWS);
        xp += 4 * NROWS;
        STEP(x0, w0)
        STEP(x1, w1)
        STEP(x2, w2)
        STEP(x3, w3)
    }
#undef STEP
    float* op = partial + (size_t)z * NROWS * VOCABSZ + (size_t)r0 * VOCABSZ + v0;
    *(float4*)(op) = a0;
    *(float4*)(op + (size_t)VOCABSZ) = a1;
    *(float4*)(op + (size_t)2 * VOCABSZ) = a2;
    *(float4*)(op + (size_t)3 * VOCABSZ) = a3;
}

// ---------------- per-(row,chunk): partial max, sumexp, top-8 ----------------
// R8: 1024 threads (32 waves/CU), 1 float4/slab per thread (all loads
// independent/in-flight), 4-barrier merge: sort-4 network -> per-wave top-8
// via shfl wave-max rounds -> 128 keys in LDS -> wave0 extracts block top-8.
template<int NZ>
__global__ __launch_bounds__(1024) void k_part(const float* __restrict__ partial,
                                               const float* __restrict__ bias,
                                               float* __restrict__ pm, float* __restrict__ ps,
                                               float* __restrict__ ptopv, int* __restrict__ ptopi) {
    int row = blockIdx.x, ch = blockIdx.y;
    int tid = threadIdx.x;
    int lane = tid & 63;
    int wv = tid >> 6;                    // 0..15
    const size_t slab = (size_t)NROWS * VOCABSZ;
    const bool valid = tid < (CHUNK / 4); // 1000 float4 positions

    float vals[4] = {-INFINITY, -INFINITY, -INFINITY, -INFINITY};
    if (valid) {
        const float4* l0 = (const float4*)(partial + (size_t)row * VOCABSZ + ch * CHUNK);
        float4 q = l0[tid];
#pragma unroll
        for (int zz = 1; zz < NZ; ++zz) {
            const float4* lz = (const float4*)(partial + slab * zz + (size_t)row * VOCABSZ + ch * CHUNK);
            float4 q2 = lz[tid];
            q.x += q2.x; q.y += q2.y; q.z += q2.z; q.w += q2.w;
        }
        float4 bb = ((const float4*)(bias + ch * CHUNK))[tid];
        vals[0] = q.x + bb.x; vals[1] = q.y + bb.y; vals[2] = q.z + bb.z; vals[3] = q.w + bb.w;
    }

    // ---- block max: wave butterfly + 16-entry LDS combine ----
    float m_t = fmaxf(fmaxf(vals[0], vals[1]), fmaxf(vals[2], vals[3]));
#pragma unroll
    for (int off = 1; off < 64; off <<= 1) m_t = fmaxf(m_t, __shfl_xor(m_t, off, 64));
    __shared__ float swred[16];
    if (lane == 0) swred[wv] = m_t;
    __syncthreads();
    float m = swred[0];
#pragma unroll
    for (int w = 1; w < 16; ++w) m = fmaxf(m, swred[w]);
    __syncthreads();   // swred reused for sums below

    // ---- block sumexp ----
    float se = 0.f;
    if (valid) {
#pragma unroll
        for (int c = 0; c < 4; ++c) se += expf(vals[c] - m);
    }
#pragma unroll
    for (int off = 1; off < 64; off <<= 1) se += __shfl_xor(se, off, 64);
    if (lane == 0) swred[wv] = se;
    __syncthreads();
    if (tid == 0) {
        float s = 0.f;
#pragma unroll
        for (int w = 0; w < 16; ++w) s += swred[w];
        pm[row * CHUNKS + ch] = m;
        ps[row * CHUNKS + ch] = s;
    }

    // ---- top-8: per-lane sort-4 -> per-wave 8 rounds wave-max -> 128-key final ----
    int gi = ch * CHUNK + tid * 4;
    unsigned long long k0 = 0ULL, k1 = 0ULL, k2 = 0ULL, k3 = 0ULL;
    if (valid) {   // keys never 0 for real values (idx < 2^31) -> 0 is a safe sentinel
        k0 = packkey(vals[0], gi);
        k1 = packkey(vals[1], gi + 1);
        k2 = packkey(vals[2], gi + 2);
        k3 = packkey(vals[3], gi + 3);
    }
    {
        unsigned long long tswp;
#define CSW(a,b) if (b > a) { tswp = a; a = b; b = tswp; }
        CSW(k0,k1) CSW(k2,k3) CSW(k0,k2) CSW(k1,k3) CSW(k1,k2)
#undef CSW
    }
    __shared__ unsigned long long skey[128];
    {
        int pos = 0;
        unsigned long long wtop[8];
#pragma unroll
        for (int r = 0; r < 8; ++r) {
            unsigned long long head = (pos == 0) ? k0 : (pos == 1) ? k1 :
                                      (pos == 2) ? k2 : (pos == 3) ? k3 : 0ULL;
            unsigned long long mx = wavemax64(head);
            if (head == mx && head != 0ULL) pos++;   // unique keys -> exactly one winner
            wtop[r] = mx;
        }
        if (lane == 0) {
#pragma unroll
            for (int r = 0; r < 8; ++r) skey[wv * 8 + r] = wtop[r];
        }
    }
    __syncthreads();
    if (tid < 64) {   // wave 0 exactly; no barriers below
        unsigned long long a = skey[tid];
        unsigned long long b2 = skey[64 + tid];
        unsigned long long hi = (a > b2) ? a : b2;
        unsigned long long lo = (a > b2) ? b2 : a;
        float* otv = ptopv + ((size_t)row * CHUNKS + ch) * 8;
        int*   oti = ptopi + ((size_t)row * CHUNKS + ch) * 8;
        int pos = 0;
#pragma unroll
        for (int r = 0; r < 8; ++r) {
            unsigned long long head = (pos == 0) ? hi : (pos == 1) ? lo : 0ULL;
            unsigned long long mx = wavemax64(head);
            if (head == mx && head != 0ULL) pos++;
            if (tid == 0) { otv[r] = unpack_val(mx); oti[r] = unpack_id(mx); }
        }
    }
}

// ---------------- merge + beam bookkeeping, one block (one wave) per batch ----------------
__global__ __launch_bounds__(64) void k_mergesel(const float* __restrict__ pm, const float* __restrict__ ps,
                                                 const float* __restrict__ ptopv, const int* __restrict__ ptopi,
                                                 int* __restrict__ alive_seq, float* __restrict__ alive_lp,
                                                 int* __restrict__ fin_seq, float* __restrict__ fin_scores,
                                                 int* __restrict__ fin_flags, int* __restrict__ batch_fin, int t) {
    int b = blockIdx.x;
    int tid = threadIdx.x;
    __shared__ int aseq_old[BEAM][MAXLEN]; __shared__ int fseq_old[BEAM][MAXLEN];
    __shared__ float s_tlp[8]; __shared__ int s_ttok[8], s_tbeam[8];
    __shared__ int s_aidx[4], s_fidx[4];
    __shared__ float s_nfsc[4]; __shared__ int s_nffl[4];
    float lpen = (float)(t + 1);

    { int k = tid >> 4, p = tid & 15;
      aseq_old[k][p] = alive_seq[(b * BEAM + k) * MAXLEN + p];
      fseq_old[k][p] = fin_seq[(b * BEAM + k) * MAXLEN + p]; }

    float rv[4]; int ri[4];
#pragma unroll
    for (int k = 0; k < 4; ++k) {
        rv[k] = ptopv[(size_t)(b * BEAM + k) * 64 + tid];
        ri[k] = ptopi[(size_t)(b * BEAM + k) * 64 + tid];
    }

    float alp[4], fsc[4]; int ffl[4];
#pragma unroll
    for (int k = 0; k < 4; ++k) {
        alp[k] = alive_lp[b * BEAM + k];
        fsc[k] = fin_scores[b * BEAM + k];
        ffl[k] = fin_flags[b * BEAM + k];
    }
    int bf_old = batch_fin[b];

    float srm[4], srl[4];
#pragma unroll
    for (int k = 0; k < 4; ++k) {
        float m = -INFINITY;
#pragma unroll
        for (int c = 0; c < CHUNKS; ++c) m = fmaxf(m, pm[(b * BEAM + k) * CHUNKS + c]);
        float s = 0.f;
#pragma unroll
        for (int c = 0; c < CHUNKS; ++c) s += ps[(b * BEAM + k) * CHUNKS + c] * expf(pm[(b * BEAM + k) * CHUNKS + c] - m);
        srm[k] = m; srl[k] = logf(s);
    }

    unsigned long long key[4];
#pragma unroll
    for (int k = 0; k < 4; ++k) {
        float sh = rv[k] - srm[k];
        float lp = sh - srl[k];
        float full = alp[k] + lp;
        float cv = full / lpen;
        key[k] = packkey(cv, k * VOCABSZ + ri[k]);
    }
    {
        unsigned long long tmp;
#define CSW(a,b) if (key[b] > key[a]) { tmp = key[a]; key[a] = key[b]; key[b] = tmp; }
        CSW(0,1) CSW(2,3) CSW(0,2) CSW(1,3) CSW(1,2)
#undef CSW
    }

    float tscore[8], tlp[8]; int ttok[8], tbeam[8], tfin[8];
    int pos = 0;
#pragma unroll
    for (int r = 0; r < 8; ++r) {
        unsigned long long head = (pos == 0) ? key[0] : (pos == 1) ? key[1] :
                                  (pos == 2) ? key[2] : (pos == 3) ? key[3] : 0ULL;
        unsigned long long mx = wavemax64(head);
        if (head == mx && head != 0ULL) pos++;
        float sc = unpack_val(mx);
        int id = unpack_id(mx);
        tscore[r] = sc;
        tlp[r] = sc * lpen;
        ttok[r] = id % VOCABSZ;
        tbeam[r] = id / VOCABSZ;
        tfin[r] = (ttok[r] == EOS_TOK) ? 1 : 0;
    }

    int aidx[4];
    {
        float curr[8];
#pragma unroll
        for (int j = 0; j < 8; ++j) curr[j] = tscore[j] + (tfin[j] ? -NEGINF : 0.0f);
        unsigned int used = 0;
#pragma unroll
        for (int r = 0; r < 4; ++r) {
            float bv = 0.f; int bj = -1;
#pragma unroll
            for (int j = 0; j < 8; ++j) {
                bool skip = (used >> j) & 1u;
                bool better = !skip && (bj < 0 || curr[j] > bv);
                if (better) { bv = curr[j]; bj = j; }
            }
            used |= 1u << bj; aidx[r] = bj;
        }
    }
    int fidx[4]; float nfsc[4]; int nffl[4];
    {
        float fscand[12]; int fflcand[12];
#pragma unroll
        for (int j = 0; j < 4; ++j) { fscand[j] = fsc[j]; fflcand[j] = ffl[j]; }
#pragma unroll
        for (int q = 0; q < 8; ++q) {
            float t1 = tscore[q] + (tfin[q] ? 0.0f : -NEGINF);
            float t2 = t1 + (bf_old ? -NEGINF : 0.0f);
            fscand[4 + q] = t2; fflcand[4 + q] = tfin[q];
        }
        unsigned int used = 0;
#pragma unroll
        for (int r = 0; r < 4; ++r) {
            float bv = 0.f; int bj = -1;
#pragma unroll
            for (int j = 0; j < 12; ++j) {
                bool skip = (used >> j) & 1u;
                bool better = !skip && (bj < 0 || fscand[j] > bv);
                if (better) { bv = fscand[j]; bj = j; }
            }
            used |= 1u << bj; fidx[r] = bj;
            nfsc[r] = bv;
        }
#pragma unroll
        for (int r = 0; r < 4; ++r) {
            int bj = fidx[r]; int fl = 0;
#pragma unroll
            for (int j = 0; j < 12; ++j) if (bj == j) fl = fflcand[j];
            nffl[r] = fl;
        }
    }

    if (tid == 0) {
#pragma unroll
        for (int r = 0; r < 8; ++r) { s_tlp[r] = tlp[r]; s_ttok[r] = ttok[r]; s_tbeam[r] = tbeam[r]; }
#pragma unroll
        for (int r = 0; r < 4; ++r) { s_aidx[r] = aidx[r]; s_fidx[r] = fidx[r]; s_nfsc[r] = nfsc[r]; s_nffl[r] = nffl[r]; }
    }
    __syncthreads();

    { int k = tid >> 4, p = tid & 15;
      int j = s_aidx[k];
      int val = (p == t + 1) ? s_ttok[j] : aseq_old[s_tbeam[j]][p];
      alive_seq[(b * BEAM + k) * MAXLEN + p] = val;
      int fi = s_fidx[k]; int fval;
      if (fi < 4) fval = fseq_old[fi][p];
      else { int q = fi - 4; fval = (p == t + 1) ? s_ttok[q] : aseq_old[s_tbeam[q]][p]; }
      fin_seq[(b * BEAM + k) * MAXLEN + p] = fval; }

    if (tid < 4) {
        alive_lp[b * BEAM + tid] = s_tlp[s_aidx[tid]];
        fin_scores[b * BEAM + tid] = s_nfsc[tid];
        fin_flags[b * BEAM + tid] = s_nffl[tid];
    }
    if (tid == 0) {
        float lb = s_tlp[s_aidx[0]] / lpen;
        float lowest = nfsc[0] * (nffl[0] ? 1.f : 0.f);
        int allf = nffl[0];
#pragma unroll
        for (int k2 = 1; k2 < 4; ++k2) {
            float pz = nfsc[k2] * (nffl[k2] ? 1.f : 0.f);
            lowest = fminf(lowest, pz);
            allf = allf && nffl[k2];
        }
        lowest = lowest + (allf ? 0.f : -NEGINF);
        batch_fin[b] = bf_old || (lowest >= lb);
    }
}

// ---------------- output: fin_seq[:,0,:] as float ----------------
__global__ __launch_bounds__(256) void k_out(const int* __restrict__ fin_seq, float* __restrict__ out) {
    int tid = threadIdx.x;
    if (tid < BATCH * MAXLEN) {
        int b = tid / MAXLEN, p = tid % MAXLEN;
        out[tid] = (float)fin_seq[(b * BEAM + 0) * MAXLEN + p];
    }
}

extern "C" void kernel_launch(void* const* d_in, const int* in_sizes, int n_in,
                              void* d_out, int out_size, void* d_ws, size_t ws_size,
                              hipStream_t stream) {
    const int*   src  = (const int*)d_in[0];
    const float* Esrc = (const float*)d_in[1];
    const float* Etgt = (const float*)d_in[2];
    const float* W    = (const float*)d_in[3];
    const float* bias = (const float*)d_in[4];
    float* out = (float*)d_out;

    const size_t slab = (size_t)NROWS * VOCABSZ * 4;  // 8.192 MB; 2 slabs (z-split d)

    char* p = (char*)d_ws;
    float* partial    = (float*)p; p += 2 * slab;
    float* pooled     = (float*)p; p += BATCH * DIM * 4;
    float* xT         = (float*)p; p += DIM * NROWS * 4;
    float* pp         = (float*)p; p += BATCH * PCH * DIM * 4;   // 256 KB
    float* pcnt       = (float*)p; p += BATCH * PCH * 4;
    float* pm         = (float*)p; p += NROWS * CHUNKS * 4;
    float* ps         = (float*)p; p += NROWS * CHUNKS * 4;
    float* ptopv      = (float*)p; p += NROWS * CHUNKS * 8 * 4;
    int*   ptopi      = (int*)p;   p += NROWS * CHUNKS * 8 * 4;
    int*   alive_seq  = (int*)p;   p += NROWS * MAXLEN * 4;
    int*   fin_seq    = (int*)p;   p += NROWS * MAXLEN * 4;
    float* alive_lp   = (float*)p; p += NROWS * 4;
    float* fin_scores = (float*)p; p += NROWS * 4;
    int*   fin_flags  = (int*)p;   p += NROWS * 4;
    int*   batch_fin  = (int*)p;   p += BATCH * 4;

    k_pool2<<<dim3(BATCH, PCH), DIM, 0, stream>>>(src, Esrc, pp, pcnt);
    k_poolred<<<BATCH, DIM, 0, stream>>>(pp, pcnt, pooled);
    k_init<<<1, 1024, 0, stream>>>(alive_seq, alive_lp, fin_seq, fin_scores, fin_flags, batch_fin);
    for (int t = 0; t < MAXLEN - 1; ++t) {
        k_x<<<NROWS, DIM, 0, stream>>>(Etgt, pooled, alive_seq, t, xT);
        k_gemm6<<<dim3(VOCABSZ / 256, 1, 2), 1024, 0, stream>>>(xT, W, partial);
        k_part<2><<<dim3(NROWS, CHUNKS), 1024, 0, stream>>>(partial, bias, pm, ps, ptopv, ptopi);
        k_mergesel<<<BATCH, 64, 0, stream>>>(pm, ps, ptopv, ptopi, alive_seq, alive_lp,
                                             fin_seq, fin_scores, fin_flags, batch_fin, t);
    }
    k_out<<<1, 256, 0, stream>>>(fin_seq, out);
}

// Round 5
// 1190.569 us; speedup vs baseline: 1.4040x; 1.0348x over previous
//
#include <hip/hip_runtime.h>
#include <math.h>

#define BATCH 16
#define SRCLEN 128
#define DIM 512
#define VOCABSZ 32000
#define BEAM 4
#define MAXLEN 16
#define NROWS (BATCH*BEAM)   // 64
#define BOS_TOK 1
#define EOS_TOK 2
#define NEGINF 1e9f
#define CHUNKS 8
#define CHUNK 4000           // VOCABSZ / CHUNKS
#define PCH 8                // pool s-chunks
#define PCL (SRCLEN/PCH)     // 16 s per chunk

// ---------------- key pack/unpack: (ordered float << 32) | (0xFFFFFFFF - id) ----------------
__device__ inline unsigned long long packkey(float v, int idx) {
    unsigned int fb = __float_as_uint(v);
    fb = fb ^ ((fb >> 31) ? 0xFFFFFFFFu : 0x80000000u);
    return ((unsigned long long)fb << 32) | (unsigned long long)(0xFFFFFFFFu - (unsigned int)idx);
}
__device__ inline float unpack_val(unsigned long long k) {
    unsigned int fb = (unsigned int)(k >> 32);
    fb = fb ^ ((fb >> 31) ? 0x80000000u : 0xFFFFFFFFu);
    return __uint_as_float(fb);
}
__device__ inline int unpack_id(unsigned long long k) {
    return (int)(0xFFFFFFFFu - (unsigned int)(k & 0xFFFFFFFFu));
}
__device__ inline unsigned long long shflxor64(unsigned long long x, int mask) {
    unsigned int lo = (unsigned int)x, hi = (unsigned int)(x >> 32);
    lo = (unsigned int)__shfl_xor((int)lo, mask, 64);
    hi = (unsigned int)__shfl_xor((int)hi, mask, 64);
    return ((unsigned long long)hi << 32) | (unsigned long long)lo;
}
__device__ inline unsigned long long wavemax64(unsigned long long k) {
#pragma unroll
    for (int off = 1; off < 64; off <<= 1) {
        unsigned long long o = shflxor64(k, off);
        k = (o > k) ? o : k;
    }
    return k;
}

// ---------------- encoder pool, phase 1: per-(b, s-chunk) partial sum + count ----------------
__global__ __launch_bounds__(512) void k_pool2(const int* __restrict__ src,
                                               const float* __restrict__ Esrc,
                                               float* __restrict__ pp, float* __restrict__ pcnt) {
    int b = blockIdx.x, c = blockIdx.y;
    int d = threadIdx.x;
    float acc = 0.f, cnt = 0.f;
#pragma unroll
    for (int s = 0; s < PCL; ++s) {
        int tok = src[b * SRCLEN + c * PCL + s];
        if (tok != 0) { acc += Esrc[(size_t)tok * DIM + d]; cnt += 1.f; }
    }
    pp[(b * PCH + c) * DIM + d] = acc;
    if (d == 0) pcnt[b * PCH + c] = cnt;
}

// ---------------- encoder pool, phase 2: reduce chunks (ascending, deterministic) ----------------
__global__ __launch_bounds__(512) void k_poolred(const float* __restrict__ pp,
                                                 const float* __restrict__ pcnt,
                                                 float* __restrict__ pooled) {
    int b = blockIdx.x;
    int d = threadIdx.x;
    float acc = 0.f, cnt = 0.f;
#pragma unroll
    for (int c = 0; c < PCH; ++c) { acc += pp[(b * PCH + c) * DIM + d]; cnt += pcnt[b * PCH + c]; }
    pooled[b * DIM + d] = acc / fmaxf(cnt, 1.f);
}

// ---------------- state init ----------------
__global__ __launch_bounds__(1024) void k_init(int* __restrict__ alive_seq, float* __restrict__ alive_lp,
                                               int* __restrict__ fin_seq, float* __restrict__ fin_scores,
                                               int* __restrict__ fin_flags, int* __restrict__ batch_fin) {
    int tid = threadIdx.x;  // 1024 = NROWS*MAXLEN
    alive_seq[tid] = (tid % MAXLEN == 0) ? BOS_TOK : 0;
    fin_seq[tid] = 0;
    if (tid < NROWS) {
        alive_lp[tid] = (tid % BEAM == 0) ? 0.f : -INFINITY;
        fin_scores[tid] = -NEGINF;
        fin_flags[tid] = 0;
    }
    if (tid < BATCH) batch_fin[tid] = 0;
}

// ---------------- decoder input, transposed: xT[d][i] = E_tgt[last_i][d] + pooled[i/4][d] ----------------
__global__ __launch_bounds__(512) void k_x(const float* __restrict__ Etgt,
                                           const float* __restrict__ pooled,
                                           const int* __restrict__ alive_seq, int t,
                                           float* __restrict__ xT) {
    int i = blockIdx.x;   // row 0..63
    int d = threadIdx.x;  // 0..511
    int last = alive_seq[i * MAXLEN + t];
    float v = Etgt[(size_t)last * DIM + d] + pooled[(i >> 2) * DIM + d];
    xT[d * NROWS + i] = v;
}

// ---------------- logits GEMM: lane = 16 rows x 4 vocab; block = 4 waves = all 64 rows ----------------
// R10 post-mortem of R9 (k_gemm6): 16 waves/block all read the SAME W columns
// (waves split rows; rows don't index W) -> per-CU VMEM = 16 x 256KB = 4MB,
// ~27us at L1's ~64B/cyc, 2x the 13.7us compute floor -> VALUBusy 30%, 57us.
// Now lane owns 16 rows x 4 vocab (acc 64 VGPR, full unroll -> static idx, no
// scratch): W replication 16x -> 4x, per-CU VMEM ~1MB (~7us) < compute floor.
// Per d-step: 1 W float4 (lanes contiguous = 1KB/instr), 4 uniform ds_read
// (broadcast, 0 conflicts), 64 FMA (128 issue-cyc) -> ~93% fma density.
// d split z=4 (GD=128, 32KB LDS) -> 500 blocks ~ 2/CU for latency hiding.
// Per-slab d-ascending accumulation; k_part<4> sums slabs (NZ=4 verified
// absmax=0 in R1; NZ=2 in R9).
template<int GDLEN>
__global__ __launch_bounds__(256) void k_gemm7(const float* __restrict__ xT,
                                               const float* __restrict__ W,
                                               float* __restrict__ partial) {
    int lane = threadIdx.x & 63;
    int wv   = threadIdx.x >> 6;            // 0..3
    int v0 = blockIdx.x * 256 + lane * 4;   // vocab quad
    int r0 = wv * 16;                       // 16-row group (wave-uniform)
    int z  = blockIdx.z;
    int d0 = z * GDLEN;

    __shared__ float xs[GDLEN * NROWS];     // 32 KB at GDLEN=128
    {
        const float4* xg = (const float4*)(xT + (size_t)d0 * NROWS);
        float4* xs4 = (float4*)xs;
#pragma unroll
        for (int i = 0; i < (GDLEN * NROWS / 4) / 256; ++i)
            xs4[i * 256 + threadIdx.x] = xg[i * 256 + threadIdx.x];
    }
    __syncthreads();

    float4 acc[16];
#pragma unroll
    for (int i = 0; i < 16; ++i) acc[i] = make_float4(0.f, 0.f, 0.f, 0.f);

    const float* wp = W + (size_t)d0 * VOCABSZ + v0;
    const float* xp = xs + r0;              // xs[d*NROWS + r]
#pragma unroll 2
    for (int d = 0; d < GDLEN; ++d) {
        float4 wq = *(const float4*)(wp);
        wp += (size_t)VOCABSZ;
#pragma unroll
        for (int rq = 0; rq < 4; ++rq) {
            float4 xr = *(const float4*)(xp + rq * 4);
            acc[rq*4+0].x = fmaf(xr.x, wq.x, acc[rq*4+0].x);
            acc[rq*4+0].y = fmaf(xr.x, wq.y, acc[rq*4+0].y);
            acc[rq*4+0].z = fmaf(xr.x, wq.z, acc[rq*4+0].z);
            acc[rq*4+0].w = fmaf(xr.x, wq.w, acc[rq*4+0].w);
            acc[rq*4+1].x = fmaf(xr.y, wq.x, acc[rq*4+1].x);
            acc[rq*4+1].y = fmaf(xr.y, wq.y, acc[rq*4+1].y);
            acc[rq*4+1].z = fmaf(xr.y, wq.z, acc[rq*4+1].z);
            acc[rq*4+1].w = fmaf(xr.y, wq.w, acc[rq*4+1].w);
            acc[rq*4+2].x = fmaf(xr.z, wq.x, acc[rq*4+2].x);
            acc[rq*4+2].y = fmaf(xr.z, wq.y, acc[rq*4+2].y);
            acc[rq*4+2].z = fmaf(xr.z, wq.z, acc[rq*4+2].z);
            acc[rq*4+2].w = fmaf(xr.z, wq.w, acc[rq*4+2].w);
            acc[rq*4+3].x = fmaf(xr.w, wq.x, acc[rq*4+3].x);
            acc[rq*4+3].y = fmaf(xr.w, wq.y, acc[rq*4+3].y);
            acc[rq*4+3].z = fmaf(xr.w, wq.z, acc[rq*4+3].z);
            acc[rq*4+3].w = fmaf(xr.w, wq.w, acc[rq*4+3].w);
        }
        xp += NROWS;
    }

    float* op = partial + (size_t)z * NROWS * VOCABSZ + (size_t)r0 * VOCABSZ + v0;
#pragma unroll
    for (int r = 0; r < 16; ++r)
        *(float4*)(op + (size_t)r * VOCABSZ) = acc[r];
}

// ---------------- per-(row,chunk): partial max, sumexp, top-8 ----------------
// R8: 1024 threads (32 waves/CU), 1 float4/slab per thread (all loads
// independent/in-flight), 4-barrier merge: sort-4 network -> per-wave top-8
// via shfl wave-max rounds -> 128 keys in LDS -> wave0 extracts block top-8.
template<int NZ>
__global__ __launch_bounds__(1024) void k_part(const float* __restrict__ partial,
                                               const float* __restrict__ bias,
                                               float* __restrict__ pm, float* __restrict__ ps,
                                               float* __restrict__ ptopv, int* __restrict__ ptopi) {
    int row = blockIdx.x, ch = blockIdx.y;
    int tid = threadIdx.x;
    int lane = tid & 63;
    int wv = tid >> 6;                    // 0..15
    const size_t slab = (size_t)NROWS * VOCABSZ;
    const bool valid = tid < (CHUNK / 4); // 1000 float4 positions

    float vals[4] = {-INFINITY, -INFINITY, -INFINITY, -INFINITY};
    if (valid) {
        const float4* l0 = (const float4*)(partial + (size_t)row * VOCABSZ + ch * CHUNK);
        float4 q = l0[tid];
#pragma unroll
        for (int zz = 1; zz < NZ; ++zz) {
            const float4* lz = (const float4*)(partial + slab * zz + (size_t)row * VOCABSZ + ch * CHUNK);
            float4 q2 = lz[tid];
            q.x += q2.x; q.y += q2.y; q.z += q2.z; q.w += q2.w;
        }
        float4 bb = ((const float4*)(bias + ch * CHUNK))[tid];
        vals[0] = q.x + bb.x; vals[1] = q.y + bb.y; vals[2] = q.z + bb.z; vals[3] = q.w + bb.w;
    }

    // ---- block max: wave butterfly + 16-entry LDS combine ----
    float m_t = fmaxf(fmaxf(vals[0], vals[1]), fmaxf(vals[2], vals[3]));
#pragma unroll
    for (int off = 1; off < 64; off <<= 1) m_t = fmaxf(m_t, __shfl_xor(m_t, off, 64));
    __shared__ float swred[16];
    if (lane == 0) swred[wv] = m_t;
    __syncthreads();
    float m = swred[0];
#pragma unroll
    for (int w = 1; w < 16; ++w) m = fmaxf(m, swred[w]);
    __syncthreads();   // swred reused for sums below

    // ---- block sumexp ----
    float se = 0.f;
    if (valid) {
#pragma unroll
        for (int c = 0; c < 4; ++c) se += expf(vals[c] - m);
    }
#pragma unroll
    for (int off = 1; off < 64; off <<= 1) se += __shfl_xor(se, off, 64);
    if (lane == 0) swred[wv] = se;
    __syncthreads();
    if (tid == 0) {
        float s = 0.f;
#pragma unroll
        for (int w = 0; w < 16; ++w) s += swred[w];
        pm[row * CHUNKS + ch] = m;
        ps[row * CHUNKS + ch] = s;
    }

    // ---- top-8: per-lane sort-4 -> per-wave 8 rounds wave-max -> 128-key final ----
    int gi = ch * CHUNK + tid * 4;
    unsigned long long k0 = 0ULL, k1 = 0ULL, k2 = 0ULL, k3 = 0ULL;
    if (valid) {   // keys never 0 for real values (idx < 2^31) -> 0 is a safe sentinel
        k0 = packkey(vals[0], gi);
        k1 = packkey(vals[1], gi + 1);
        k2 = packkey(vals[2], gi + 2);
        k3 = packkey(vals[3], gi + 3);
    }
    {
        unsigned long long tswp;
#define CSW(a,b) if (b > a) { tswp = a; a = b; b = tswp; }
        CSW(k0,k1) CSW(k2,k3) CSW(k0,k2) CSW(k1,k3) CSW(k1,k2)
#undef CSW
    }
    __shared__ unsigned long long skey[128];
    {
        int pos = 0;
        unsigned long long wtop[8];
#pragma unroll
        for (int r = 0; r < 8; ++r) {
            unsigned long long head = (pos == 0) ? k0 : (pos == 1) ? k1 :
                                      (pos == 2) ? k2 : (pos == 3) ? k3 : 0ULL;
            unsigned long long mx = wavemax64(head);
            if (head == mx && head != 0ULL) pos++;   // unique keys -> exactly one winner
            wtop[r] = mx;
        }
        if (lane == 0) {
#pragma unroll
            for (int r = 0; r < 8; ++r) skey[wv * 8 + r] = wtop[r];
        }
    }
    __syncthreads();
    if (tid < 64) {   // wave 0 exactly; no barriers below
        unsigned long long a = skey[tid];
        unsigned long long b2 = skey[64 + tid];
        unsigned long long hi = (a > b2) ? a : b2;
        unsigned long long lo = (a > b2) ? b2 : a;
        float* otv = ptopv + ((size_t)row * CHUNKS + ch) * 8;
        int*   oti = ptopi + ((size_t)row * CHUNKS + ch) * 8;
        int pos = 0;
#pragma unroll
        for (int r = 0; r < 8; ++r) {
            unsigned long long head = (pos == 0) ? hi : (pos == 1) ? lo : 0ULL;
            unsigned long long mx = wavemax64(head);
            if (head == mx && head != 0ULL) pos++;
            if (tid == 0) { otv[r] = unpack_val(mx); oti[r] = unpack_id(mx); }
        }
    }
}

// ---------------- merge + beam bookkeeping, one block (one wave) per batch ----------------
__global__ __launch_bounds__(64) void k_mergesel(const float* __restrict__ pm, const float* __restrict__ ps,
                                                 const float* __restrict__ ptopv, const int* __restrict__ ptopi,
                                                 int* __restrict__ alive_seq, float* __restrict__ alive_lp,
                                                 int* __restrict__ fin_seq, float* __restrict__ fin_scores,
                                                 int* __restrict__ fin_flags, int* __restrict__ batch_fin, int t) {
    int b = blockIdx.x;
    int tid = threadIdx.x;
    __shared__ int aseq_old[BEAM][MAXLEN]; __shared__ int fseq_old[BEAM][MAXLEN];
    __shared__ float s_tlp[8]; __shared__ int s_ttok[8], s_tbeam[8];
    __shared__ int s_aidx[4], s_fidx[4];
    __shared__ float s_nfsc[4]; __shared__ int s_nffl[4];
    float lpen = (float)(t + 1);

    { int k = tid >> 4, p = tid & 15;
      aseq_old[k][p] = alive_seq[(b * BEAM + k) * MAXLEN + p];
      fseq_old[k][p] = fin_seq[(b * BEAM + k) * MAXLEN + p]; }

    float rv[4]; int ri[4];
#pragma unroll
    for (int k = 0; k < 4; ++k) {
        rv[k] = ptopv[(size_t)(b * BEAM + k) * 64 + tid];
        ri[k] = ptopi[(size_t)(b * BEAM + k) * 64 + tid];
    }

    float alp[4], fsc[4]; int ffl[4];
#pragma unroll
    for (int k = 0; k < 4; ++k) {
        alp[k] = alive_lp[b * BEAM + k];
        fsc[k] = fin_scores[b * BEAM + k];
        ffl[k] = fin_flags[b * BEAM + k];
    }
    int bf_old = batch_fin[b];

    float srm[4], srl[4];
#pragma unroll
    for (int k = 0; k < 4; ++k) {
        float m = -INFINITY;
#pragma unroll
        for (int c = 0; c < CHUNKS; ++c) m = fmaxf(m, pm[(b * BEAM + k) * CHUNKS + c]);
        float s = 0.f;
#pragma unroll
        for (int c = 0; c < CHUNKS; ++c) s += ps[(b * BEAM + k) * CHUNKS + c] * expf(pm[(b * BEAM + k) * CHUNKS + c] - m);
        srm[k] = m; srl[k] = logf(s);
    }

    unsigned long long key[4];
#pragma unroll
    for (int k = 0; k < 4; ++k) {
        float sh = rv[k] - srm[k];
        float lp = sh - srl[k];
        float full = alp[k] + lp;
        float cv = full / lpen;
        key[k] = packkey(cv, k * VOCABSZ + ri[k]);
    }
    {
        unsigned long long tmp;
#define CSW(a,b) if (key[b] > key[a]) { tmp = key[a]; key[a] = key[b]; key[b] = tmp; }
        CSW(0,1) CSW(2,3) CSW(0,2) CSW(1,3) CSW(1,2)
#undef CSW
    }

    float tscore[8], tlp[8]; int ttok[8], tbeam[8], tfin[8];
    int pos = 0;
#pragma unroll
    for (int r = 0; r < 8; ++r) {
        unsigned long long head = (pos == 0) ? key[0] : (pos == 1) ? key[1] :
                                  (pos == 2) ? key[2] : (pos == 3) ? key[3] : 0ULL;
        unsigned long long mx = wavemax64(head);
        if (head == mx && head != 0ULL) pos++;
        float sc = unpack_val(mx);
        int id = unpack_id(mx);
        tscore[r] = sc;
        tlp[r] = sc * lpen;
        ttok[r] = id % VOCABSZ;
        tbeam[r] = id / VOCABSZ;
        tfin[r] = (ttok[r] == EOS_TOK) ? 1 : 0;
    }

    int aidx[4];
    {
        float curr[8];
#pragma unroll
        for (int j = 0; j < 8; ++j) curr[j] = tscore[j] + (tfin[j] ? -NEGINF : 0.0f);
        unsigned int used = 0;
#pragma unroll
        for (int r = 0; r < 4; ++r) {
            float bv = 0.f; int bj = -1;
#pragma unroll
            for (int j = 0; j < 8; ++j) {
                bool skip = (used >> j) & 1u;
                bool better = !skip && (bj < 0 || curr[j] > bv);
                if (better) { bv = curr[j]; bj = j; }
            }
            used |= 1u << bj; aidx[r] = bj;
        }
    }
    int fidx[4]; float nfsc[4]; int nffl[4];
    {
        float fscand[12]; int fflcand[12];
#pragma unroll
        for (int j = 0; j < 4; ++j) { fscand[j] = fsc[j]; fflcand[j] = ffl[j]; }
#pragma unroll
        for (int q = 0; q < 8; ++q) {
            float t1 = tscore[q] + (tfin[q] ? 0.0f : -NEGINF);
            float t2 = t1 + (bf_old ? -NEGINF : 0.0f);
            fscand[4 + q] = t2; fflcand[4 + q] = tfin[q];
        }
        unsigned int used = 0;
#pragma unroll
        for (int r = 0; r < 4; ++r) {
            float bv = 0.f; int bj = -1;
#pragma unroll
            for (int j = 0; j < 12; ++j) {
                bool skip = (used >> j) & 1u;
                bool better = !skip && (bj < 0 || fscand[j] > bv);
                if (better) { bv = fscand[j]; bj = j; }
            }
            used |= 1u << bj; fidx[r] = bj;
            nfsc[r] = bv;
        }
#pragma unroll
        for (int r = 0; r < 4; ++r) {
            int bj = fidx[r]; int fl = 0;
#pragma unroll
            for (int j = 0; j < 12; ++j) if (bj == j) fl = fflcand[j];
            nffl[r] = fl;
        }
    }

    if (tid == 0) {
#pragma unroll
        for (int r = 0; r < 8; ++r) { s_tlp[r] = tlp[r]; s_ttok[r] = ttok[r]; s_tbeam[r] = tbeam[r]; }
#pragma unroll
        for (int r = 0; r < 4; ++r) { s_aidx[r] = aidx[r]; s_fidx[r] = fidx[r]; s_nfsc[r] = nfsc[r]; s_nffl[r] = nffl[r]; }
    }
    __syncthreads();

    { int k = tid >> 4, p = tid & 15;
      int j = s_aidx[k];
      int val = (p == t + 1) ? s_ttok[j] : aseq_old[s_tbeam[j]][p];
      alive_seq[(b * BEAM + k) * MAXLEN + p] = val;
      int fi = s_fidx[k]; int fval;
      if (fi < 4) fval = fseq_old[fi][p];
      else { int q = fi - 4; fval = (p == t + 1) ? s_ttok[q] : aseq_old[s_tbeam[q]][p]; }
      fin_seq[(b * BEAM + k) * MAXLEN + p] = fval; }

    if (tid < 4) {
        alive_lp[b * BEAM + tid] = s_tlp[s_aidx[tid]];
        fin_scores[b * BEAM + tid] = s_nfsc[tid];
        fin_flags[b * BEAM + tid] = s_nffl[tid];
    }
    if (tid == 0) {
        float lb = s_tlp[s_aidx[0]] / lpen;
        float lowest = nfsc[0] * (nffl[0] ? 1.f : 0.f);
        int allf = nffl[0];
#pragma unroll
        for (int k2 = 1; k2 < 4; ++k2) {
            float pz = nfsc[k2] * (nffl[k2] ? 1.f : 0.f);
            lowest = fminf(lowest, pz);
            allf = allf && nffl[k2];
        }
        lowest = lowest + (allf ? 0.f : -NEGINF);
        batch_fin[b] = bf_old || (lowest >= lb);
    }
}

// ---------------- output: fin_seq[:,0,:] as float ----------------
__global__ __launch_bounds__(256) void k_out(const int* __restrict__ fin_seq, float* __restrict__ out) {
    int tid = threadIdx.x;
    if (tid < BATCH * MAXLEN) {
        int b = tid / MAXLEN, p = tid % MAXLEN;
        out[tid] = (float)fin_seq[(b * BEAM + 0) * MAXLEN + p];
    }
}

extern "C" void kernel_launch(void* const* d_in, const int* in_sizes, int n_in,
                              void* d_out, int out_size, void* d_ws, size_t ws_size,
                              hipStream_t stream) {
    const int*   src  = (const int*)d_in[0];
    const float* Esrc = (const float*)d_in[1];
    const float* Etgt = (const float*)d_in[2];
    const float* W    = (const float*)d_in[3];
    const float* bias = (const float*)d_in[4];
    float* out = (float*)d_out;

    const size_t slab = (size_t)NROWS * VOCABSZ * 4;  // 8.192 MB
    const bool big = ws_size >= 4 * slab + (1u << 20); // 4 z-slabs fit? (R1: yes)
    const int NZ = big ? 4 : 2;

    char* p = (char*)d_ws;
    float* partial    = (float*)p; p += NZ * slab;
    float* pooled     = (float*)p; p += BATCH * DIM * 4;
    float* xT         = (float*)p; p += DIM * NROWS * 4;
    float* pp         = (float*)p; p += BATCH * PCH * DIM * 4;   // 256 KB
    float* pcnt       = (float*)p; p += BATCH * PCH * 4;
    float* pm         = (float*)p; p += NROWS * CHUNKS * 4;
    float* ps         = (float*)p; p += NROWS * CHUNKS * 4;
    float* ptopv      = (float*)p; p += NROWS * CHUNKS * 8 * 4;
    int*   ptopi      = (int*)p;   p += NROWS * CHUNKS * 8 * 4;
    int*   alive_seq  = (int*)p;   p += NROWS * MAXLEN * 4;
    int*   fin_seq    = (int*)p;   p += NROWS * MAXLEN * 4;
    float* alive_lp   = (float*)p; p += NROWS * 4;
    float* fin_scores = (float*)p; p += NROWS * 4;
    int*   fin_flags  = (int*)p;   p += NROWS * 4;
    int*   batch_fin  = (int*)p;   p += BATCH * 4;

    k_pool2<<<dim3(BATCH, PCH), DIM, 0, stream>>>(src, Esrc, pp, pcnt);
    k_poolred<<<BATCH, DIM, 0, stream>>>(pp, pcnt, pooled);
    k_init<<<1, 1024, 0, stream>>>(alive_seq, alive_lp, fin_seq, fin_scores, fin_flags, batch_fin);
    for (int t = 0; t < MAXLEN - 1; ++t) {
        k_x<<<NROWS, DIM, 0, stream>>>(Etgt, pooled, alive_seq, t, xT);
        if (big) {
            k_gemm7<DIM/4><<<dim3(VOCABSZ / 256, 1, 4), 256, 0, stream>>>(xT, W, partial);
            k_part<4><<<dim3(NROWS, CHUNKS), 1024, 0, stream>>>(partial, bias, pm, ps, ptopv, ptopi);
        } else {
            k_gemm7<DIM/2><<<dim3(VOCABSZ / 256, 1, 2), 256, 0, stream>>>(xT, W, partial);
            k_part<2><<<dim3(NROWS, CHUNKS), 1024, 0, stream>>>(partial, bias, pm, ps, ptopv, ptopi);
        }
        k_mergesel<<<BATCH, 64, 0, stream>>>(pm, ps, ptopv, ptopi, alive_seq, alive_lp,
                                             fin_seq, fin_scores, fin_flags, batch_fin, t);
    }
    k_out<<<1, 256, 0, stream>>>(fin_seq, out);
}

// Round 6
// 1137.801 us; speedup vs baseline: 1.4691x; 1.0464x over previous
//
#include <hip/hip_runtime.h>
#include <math.h>

#define BATCH 16
#define SRCLEN 128
#define DIM 512
#define VOCABSZ 32000
#define BEAM 4
#define MAXLEN 16
#define NROWS (BATCH*BEAM)   // 64
#define BOS_TOK 1
#define EOS_TOK 2
#define NEGINF 1e9f
#define CHUNKS 8
#define CHUNK 4000           // VOCABSZ / CHUNKS
#define PCH 8                // pool s-chunks
#define PCL (SRCLEN/PCH)     // 16 s per chunk

// ---------------- key pack/unpack: (ordered float << 32) | (0xFFFFFFFF - id) ----------------
__device__ inline unsigned long long packkey(float v, int idx) {
    unsigned int fb = __float_as_uint(v);
    fb = fb ^ ((fb >> 31) ? 0xFFFFFFFFu : 0x80000000u);
    return ((unsigned long long)fb << 32) | (unsigned long long)(0xFFFFFFFFu - (unsigned int)idx);
}
__device__ inline float unpack_val(unsigned long long k) {
    unsigned int fb = (unsigned int)(k >> 32);
    fb = fb ^ ((fb >> 31) ? 0x80000000u : 0xFFFFFFFFu);
    return __uint_as_float(fb);
}
__device__ inline int unpack_id(unsigned long long k) {
    return (int)(0xFFFFFFFFu - (unsigned int)(k & 0xFFFFFFFFu));
}
__device__ inline unsigned long long shflxor64(unsigned long long x, int mask) {
    unsigned int lo = (unsigned int)x, hi = (unsigned int)(x >> 32);
    lo = (unsigned int)__shfl_xor((int)lo, mask, 64);
    hi = (unsigned int)__shfl_xor((int)hi, mask, 64);
    return ((unsigned long long)hi << 32) | (unsigned long long)lo;
}
__device__ inline unsigned long long wavemax64(unsigned long long k) {
#pragma unroll
    for (int off = 1; off < 64; off <<= 1) {
        unsigned long long o = shflxor64(k, off);
        k = (o > k) ? o : k;
    }
    return k;
}

// ---------------- encoder pool, phase 1: per-(b, s-chunk) partial sum + count ----------------
__global__ __launch_bounds__(512) void k_pool2(const int* __restrict__ src,
                                               const float* __restrict__ Esrc,
                                               float* __restrict__ pp, float* __restrict__ pcnt) {
    int b = blockIdx.x, c = blockIdx.y;
    int d = threadIdx.x;
    float acc = 0.f, cnt = 0.f;
#pragma unroll
    for (int s = 0; s < PCL; ++s) {
        int tok = src[b * SRCLEN + c * PCL + s];
        if (tok != 0) { acc += Esrc[(size_t)tok * DIM + d]; cnt += 1.f; }
    }
    pp[(b * PCH + c) * DIM + d] = acc;
    if (d == 0) pcnt[b * PCH + c] = cnt;
}

// ---------------- encoder pool, phase 2: reduce chunks (ascending, deterministic) ----------------
__global__ __launch_bounds__(512) void k_poolred(const float* __restrict__ pp,
                                                 const float* __restrict__ pcnt,
                                                 float* __restrict__ pooled) {
    int b = blockIdx.x;
    int d = threadIdx.x;
    float acc = 0.f, cnt = 0.f;
#pragma unroll
    for (int c = 0; c < PCH; ++c) { acc += pp[(b * PCH + c) * DIM + d]; cnt += pcnt[b * PCH + c]; }
    pooled[b * DIM + d] = acc / fmaxf(cnt, 1.f);
}

// ---------------- state init ----------------
__global__ __launch_bounds__(1024) void k_init(int* __restrict__ alive_seq, float* __restrict__ alive_lp,
                                               int* __restrict__ fin_seq, float* __restrict__ fin_scores,
                                               int* __restrict__ fin_flags, int* __restrict__ batch_fin) {
    int tid = threadIdx.x;  // 1024 = NROWS*MAXLEN
    alive_seq[tid] = (tid % MAXLEN == 0) ? BOS_TOK : 0;
    fin_seq[tid] = 0;
    if (tid < NROWS) {
        alive_lp[tid] = (tid % BEAM == 0) ? 0.f : -INFINITY;
        fin_scores[tid] = -NEGINF;
        fin_flags[tid] = 0;
    }
    if (tid < BATCH) batch_fin[tid] = 0;
}

// ---------------- decoder input, transposed: xT[d][i] = E_tgt[last_i][d] + pooled[i/4][d] ----------------
__global__ __launch_bounds__(512) void k_x(const float* __restrict__ Etgt,
                                           const float* __restrict__ pooled,
                                           const int* __restrict__ alive_seq, int t,
                                           float* __restrict__ xT) {
    int i = blockIdx.x;   // row 0..63
    int d = threadIdx.x;  // 0..511
    int last = alive_seq[i * MAXLEN + t];
    float v = Etgt[(size_t)last * DIM + d] + pooled[(i >> 2) * DIM + d];
    xT[d * NROWS + i] = v;
}

// ---------------- logits GEMM: lane = 16 rows x 4 vocab; x via wide scalar loads; no LDS ----------------
// R11 post-mortem of R10 (k_gemm7): occupancy 17% (500 blocks x 4 waves = 2/SIMD)
// -> W-load + ds_read latency exposed, VALU 24%, 65us. Two coordinated fixes:
// (1) x off LDS: 16 wave-uniform floats per d-step via readfirstlane-uniform
//     pointer -> one s_load_dwordx16 (SMEM path; no LDS unit pressure, no
//     barriers, no 32KB footprint). 64 FMA per s_load vs R7's 4 -> no
//     serialization. (2) z=8 (GDLEN=64): 1000 blocks ~ 15.6 waves/CU (49% cap),
//     2x in-flight W loads. W replication stays 4x (~1MB/CU L1 < compute floor);
//     W global demand stays 1x. Workspace-guarded z=8/4/2.
// Per-slab d-ascending accumulation; k_part<NZ> sums slabs (NZ=4 verified
// absmax=0 in R1/R5, NZ=2 in R4).
template<int GDLEN>
__global__ __launch_bounds__(256) void k_gemm8(const float* __restrict__ xT,
                                               const float* __restrict__ W,
                                               float* __restrict__ partial) {
    int lane = threadIdx.x & 63;
    int r0 = __builtin_amdgcn_readfirstlane((threadIdx.x >> 6) * 16);  // wave-uniform row base
    int v0 = blockIdx.x * 256 + lane * 4;   // vocab quad
    int z  = blockIdx.z;
    int d0 = z * GDLEN;

    float4 acc[16];
#pragma unroll
    for (int i = 0; i < 16; ++i) acc[i] = make_float4(0.f, 0.f, 0.f, 0.f);

    const float*  wp = W + (size_t)d0 * VOCABSZ + v0;
    const float4* xq = (const float4*)(xT + (size_t)d0 * NROWS + r0);  // uniform; 4 float4 per d-step
#pragma unroll 2
    for (int d = 0; d < GDLEN; ++d) {
        float4 wq = *(const float4*)(wp);
        wp += (size_t)VOCABSZ;
        float4 xa = xq[0], xb = xq[1], xc = xq[2], xd = xq[3];   // s_load_dwordx16 (uniform)
        xq += NROWS / 4;
        float xv[16] = {xa.x, xa.y, xa.z, xa.w, xb.x, xb.y, xb.z, xb.w,
                        xc.x, xc.y, xc.z, xc.w, xd.x, xd.y, xd.z, xd.w};
#pragma unroll
        for (int i = 0; i < 16; ++i) {
            acc[i].x = fmaf(xv[i], wq.x, acc[i].x);
            acc[i].y = fmaf(xv[i], wq.y, acc[i].y);
            acc[i].z = fmaf(xv[i], wq.z, acc[i].z);
            acc[i].w = fmaf(xv[i], wq.w, acc[i].w);
        }
    }

    float* op = partial + (size_t)z * NROWS * VOCABSZ + (size_t)r0 * VOCABSZ + v0;
#pragma unroll
    for (int r = 0; r < 16; ++r)
        *(float4*)(op + (size_t)r * VOCABSZ) = acc[r];
}

// ---------------- per-(row,chunk): partial max, sumexp, top-8 ----------------
// R8: 1024 threads (32 waves/CU), 1 float4/slab per thread (all loads
// independent/in-flight), 4-barrier merge: sort-4 network -> per-wave top-8
// via shfl wave-max rounds -> 128 keys in LDS -> wave0 extracts block top-8.
template<int NZ>
__global__ __launch_bounds__(1024) void k_part(const float* __restrict__ partial,
                                               const float* __restrict__ bias,
                                               float* __restrict__ pm, float* __restrict__ ps,
                                               float* __restrict__ ptopv, int* __restrict__ ptopi) {
    int row = blockIdx.x, ch = blockIdx.y;
    int tid = threadIdx.x;
    int lane = tid & 63;
    int wv = tid >> 6;                    // 0..15
    const size_t slab = (size_t)NROWS * VOCABSZ;
    const bool valid = tid < (CHUNK / 4); // 1000 float4 positions

    float vals[4] = {-INFINITY, -INFINITY, -INFINITY, -INFINITY};
    if (valid) {
        const float4* l0 = (const float4*)(partial + (size_t)row * VOCABSZ + ch * CHUNK);
        float4 q = l0[tid];
#pragma unroll
        for (int zz = 1; zz < NZ; ++zz) {
            const float4* lz = (const float4*)(partial + slab * zz + (size_t)row * VOCABSZ + ch * CHUNK);
            float4 q2 = lz[tid];
            q.x += q2.x; q.y += q2.y; q.z += q2.z; q.w += q2.w;
        }
        float4 bb = ((const float4*)(bias + ch * CHUNK))[tid];
        vals[0] = q.x + bb.x; vals[1] = q.y + bb.y; vals[2] = q.z + bb.z; vals[3] = q.w + bb.w;
    }

    // ---- block max: wave butterfly + 16-entry LDS combine ----
    float m_t = fmaxf(fmaxf(vals[0], vals[1]), fmaxf(vals[2], vals[3]));
#pragma unroll
    for (int off = 1; off < 64; off <<= 1) m_t = fmaxf(m_t, __shfl_xor(m_t, off, 64));
    __shared__ float swred[16];
    if (lane == 0) swred[wv] = m_t;
    __syncthreads();
    float m = swred[0];
#pragma unroll
    for (int w = 1; w < 16; ++w) m = fmaxf(m, swred[w]);
    __syncthreads();   // swred reused for sums below

    // ---- block sumexp ----
    float se = 0.f;
    if (valid) {
#pragma unroll
        for (int c = 0; c < 4; ++c) se += expf(vals[c] - m);
    }
#pragma unroll
    for (int off = 1; off < 64; off <<= 1) se += __shfl_xor(se, off, 64);
    if (lane == 0) swred[wv] = se;
    __syncthreads();
    if (tid == 0) {
        float s = 0.f;
#pragma unroll
        for (int w = 0; w < 16; ++w) s += swred[w];
        pm[row * CHUNKS + ch] = m;
        ps[row * CHUNKS + ch] = s;
    }

    // ---- top-8: per-lane sort-4 -> per-wave 8 rounds wave-max -> 128-key final ----
    int gi = ch * CHUNK + tid * 4;
    unsigned long long k0 = 0ULL, k1 = 0ULL, k2 = 0ULL, k3 = 0ULL;
    if (valid) {   // keys never 0 for real values (idx < 2^31) -> 0 is a safe sentinel
        k0 = packkey(vals[0], gi);
        k1 = packkey(vals[1], gi + 1);
        k2 = packkey(vals[2], gi + 2);
        k3 = packkey(vals[3], gi + 3);
    }
    {
        unsigned long long tswp;
#define CSW(a,b) if (b > a) { tswp = a; a = b; b = tswp; }
        CSW(k0,k1) CSW(k2,k3) CSW(k0,k2) CSW(k1,k3) CSW(k1,k2)
#undef CSW
    }
    __shared__ unsigned long long skey[128];
    {
        int pos = 0;
        unsigned long long wtop[8];
#pragma unroll
        for (int r = 0; r < 8; ++r) {
            unsigned long long head = (pos == 0) ? k0 : (pos == 1) ? k1 :
                                      (pos == 2) ? k2 : (pos == 3) ? k3 : 0ULL;
            unsigned long long mx = wavemax64(head);
            if (head == mx && head != 0ULL) pos++;   // unique keys -> exactly one winner
            wtop[r] = mx;
        }
        if (lane == 0) {
#pragma unroll
            for (int r = 0; r < 8; ++r) skey[wv * 8 + r] = wtop[r];
        }
    }
    __syncthreads();
    if (tid < 64) {   // wave 0 exactly; no barriers below
        unsigned long long a = skey[tid];
        unsigned long long b2 = skey[64 + tid];
        unsigned long long hi = (a > b2) ? a : b2;
        unsigned long long lo = (a > b2) ? b2 : a;
        float* otv = ptopv + ((size_t)row * CHUNKS + ch) * 8;
        int*   oti = ptopi + ((size_t)row * CHUNKS + ch) * 8;
        int pos = 0;
#pragma unroll
        for (int r = 0; r < 8; ++r) {
            unsigned long long head = (pos == 0) ? hi : (pos == 1) ? lo : 0ULL;
            unsigned long long mx = wavemax64(head);
            if (head == mx && head != 0ULL) pos++;
            if (tid == 0) { otv[r] = unpack_val(mx); oti[r] = unpack_id(mx); }
        }
    }
}

// ---------------- merge + beam bookkeeping, one block (one wave) per batch ----------------
__global__ __launch_bounds__(64) void k_mergesel(const float* __restrict__ pm, const float* __restrict__ ps,
                                                 const float* __restrict__ ptopv, const int* __restrict__ ptopi,
                                                 int* __restrict__ alive_seq, float* __restrict__ alive_lp,
                                                 int* __restrict__ fin_seq, float* __restrict__ fin_scores,
                                                 int* __restrict__ fin_flags, int* __restrict__ batch_fin, int t) {
    int b = blockIdx.x;
    int tid = threadIdx.x;
    __shared__ int aseq_old[BEAM][MAXLEN]; __shared__ int fseq_old[BEAM][MAXLEN];
    __shared__ float s_tlp[8]; __shared__ int s_ttok[8], s_tbeam[8];
    __shared__ int s_aidx[4], s_fidx[4];
    __shared__ float s_nfsc[4]; __shared__ int s_nffl[4];
    float lpen = (float)(t + 1);

    { int k = tid >> 4, p = tid & 15;
      aseq_old[k][p] = alive_seq[(b * BEAM + k) * MAXLEN + p];
      fseq_old[k][p] = fin_seq[(b * BEAM + k) * MAXLEN + p]; }

    float rv[4]; int ri[4];
#pragma unroll
    for (int k = 0; k < 4; ++k) {
        rv[k] = ptopv[(size_t)(b * BEAM + k) * 64 + tid];
        ri[k] = ptopi[(size_t)(b * BEAM + k) * 64 + tid];
    }

    float alp[4], fsc[4]; int ffl[4];
#pragma unroll
    for (int k = 0; k < 4; ++k) {
        alp[k] = alive_lp[b * BEAM + k];
        fsc[k] = fin_scores[b * BEAM + k];
        ffl[k] = fin_flags[b * BEAM + k];
    }
    int bf_old = batch_fin[b];

    float srm[4], srl[4];
#pragma unroll
    for (int k = 0; k < 4; ++k) {
        float m = -INFINITY;
#pragma unroll
        for (int c = 0; c < CHUNKS; ++c) m = fmaxf(m, pm[(b * BEAM + k) * CHUNKS + c]);
        float s = 0.f;
#pragma unroll
        for (int c = 0; c < CHUNKS; ++c) s += ps[(b * BEAM + k) * CHUNKS + c] * expf(pm[(b * BEAM + k) * CHUNKS + c] - m);
        srm[k] = m; srl[k] = logf(s);
    }

    unsigned long long key[4];
#pragma unroll
    for (int k = 0; k < 4; ++k) {
        float sh = rv[k] - srm[k];
        float lp = sh - srl[k];
        float full = alp[k] + lp;
        float cv = full / lpen;
        key[k] = packkey(cv, k * VOCABSZ + ri[k]);
    }
    {
        unsigned long long tmp;
#define CSW(a,b) if (key[b] > key[a]) { tmp = key[a]; key[a] = key[b]; key[b] = tmp; }
        CSW(0,1) CSW(2,3) CSW(0,2) CSW(1,3) CSW(1,2)
#undef CSW
    }

    float tscore[8], tlp[8]; int ttok[8], tbeam[8], tfin[8];
    int pos = 0;
#pragma unroll
    for (int r = 0; r < 8; ++r) {
        unsigned long long head = (pos == 0) ? key[0] : (pos == 1) ? key[1] :
                                  (pos == 2) ? key[2] : (pos == 3) ? key[3] : 0ULL;
        unsigned long long mx = wavemax64(head);
        if (head == mx && head != 0ULL) pos++;
        float sc = unpack_val(mx);
        int id = unpack_id(mx);
        tscore[r] = sc;
        tlp[r] = sc * lpen;
        ttok[r] = id % VOCABSZ;
        tbeam[r] = id / VOCABSZ;
        tfin[r] = (ttok[r] == EOS_TOK) ? 1 : 0;
    }

    int aidx[4];
    {
        float curr[8];
#pragma unroll
        for (int j = 0; j < 8; ++j) curr[j] = tscore[j] + (tfin[j] ? -NEGINF : 0.0f);
        unsigned int used = 0;
#pragma unroll
        for (int r = 0; r < 4; ++r) {
            float bv = 0.f; int bj = -1;
#pragma unroll
            for (int j = 0; j < 8; ++j) {
                bool skip = (used >> j) & 1u;
                bool better = !skip && (bj < 0 || curr[j] > bv);
                if (better) { bv = curr[j]; bj = j; }
            }
            used |= 1u << bj; aidx[r] = bj;
        }
    }
    int fidx[4]; float nfsc[4]; int nffl[4];
    {
        float fscand[12]; int fflcand[12];
#pragma unroll
        for (int j = 0; j < 4; ++j) { fscand[j] = fsc[j]; fflcand[j] = ffl[j]; }
#pragma unroll
        for (int q = 0; q < 8; ++q) {
            float t1 = tscore[q] + (tfin[q] ? 0.0f : -NEGINF);
            float t2 = t1 + (bf_old ? -NEGINF : 0.0f);
            fscand[4 + q] = t2; fflcand[4 + q] = tfin[q];
        }
        unsigned int used = 0;
#pragma unroll
        for (int r = 0; r < 4; ++r) {
            float bv = 0.f; int bj = -1;
#pragma unroll
            for (int j = 0; j < 12; ++j) {
                bool skip = (used >> j) & 1u;
                bool better = !skip && (bj < 0 || fscand[j] > bv);
                if (better) { bv = fscand[j]; bj = j; }
            }
            used |= 1u << bj; fidx[r] = bj;
            nfsc[r] = bv;
        }
#pragma unroll
        for (int r = 0; r < 4; ++r) {
            int bj = fidx[r]; int fl = 0;
#pragma unroll
            for (int j = 0; j < 12; ++j) if (bj == j) fl = fflcand[j];
            nffl[r] = fl;
        }
    }

    if (tid == 0) {
#pragma unroll
        for (int r = 0; r < 8; ++r) { s_tlp[r] = tlp[r]; s_ttok[r] = ttok[r]; s_tbeam[r] = tbeam[r]; }
#pragma unroll
        for (int r = 0; r < 4; ++r) { s_aidx[r] = aidx[r]; s_fidx[r] = fidx[r]; s_nfsc[r] = nfsc[r]; s_nffl[r] = nffl[r]; }
    }
    __syncthreads();

    { int k = tid >> 4, p = tid & 15;
      int j = s_aidx[k];
      int val = (p == t + 1) ? s_ttok[j] : aseq_old[s_tbeam[j]][p];
      alive_seq[(b * BEAM + k) * MAXLEN + p] = val;
      int fi = s_fidx[k]; int fval;
      if (fi < 4) fval = fseq_old[fi][p];
      else { int q = fi - 4; fval = (p == t + 1) ? s_ttok[q] : aseq_old[s_tbeam[q]][p]; }
      fin_seq[(b * BEAM + k) * MAXLEN + p] = fval; }

    if (tid < 4) {
        alive_lp[b * BEAM + tid] = s_tlp[s_aidx[tid]];
        fin_scores[b * BEAM + tid] = s_nfsc[tid];
        fin_flags[b * BEAM + tid] = s_nffl[tid];
    }
    if (tid == 0) {
        float lb = s_tlp[s_aidx[0]] / lpen;
        float lowest = nfsc[0] * (nffl[0] ? 1.f : 0.f);
        int allf = nffl[0];
#pragma unroll
        for (int k2 = 1; k2 < 4; ++k2) {
            float pz = nfsc[k2] * (nffl[k2] ? 1.f : 0.f);
            lowest = fminf(lowest, pz);
            allf = allf && nffl[k2];
        }
        lowest = lowest + (allf ? 0.f : -NEGINF);
        batch_fin[b] = bf_old || (lowest >= lb);
    }
}

// ---------------- output: fin_seq[:,0,:] as float ----------------
__global__ __launch_bounds__(256) void k_out(const int* __restrict__ fin_seq, float* __restrict__ out) {
    int tid = threadIdx.x;
    if (tid < BATCH * MAXLEN) {
        int b = tid / MAXLEN, p = tid % MAXLEN;
        out[tid] = (float)fin_seq[(b * BEAM + 0) * MAXLEN + p];
    }
}

extern "C" void kernel_launch(void* const* d_in, const int* in_sizes, int n_in,
                              void* d_out, int out_size, void* d_ws, size_t ws_size,
                              hipStream_t stream) {
    const int*   src  = (const int*)d_in[0];
    const float* Esrc = (const float*)d_in[1];
    const float* Etgt = (const float*)d_in[2];
    const float* W    = (const float*)d_in[3];
    const float* bias = (const float*)d_in[4];
    float* out = (float*)d_out;

    const size_t slab = (size_t)NROWS * VOCABSZ * 4;  // 8.192 MB
    const bool big8 = ws_size >= 8 * slab + (2u << 20);
    const bool big4 = ws_size >= 4 * slab + (2u << 20);
    const int NZ = big8 ? 8 : (big4 ? 4 : 2);

    char* p = (char*)d_ws;
    float* partial    = (float*)p; p += NZ * slab;
    float* pooled     = (float*)p; p += BATCH * DIM * 4;
    float* xT         = (float*)p; p += DIM * NROWS * 4;
    float* pp         = (float*)p; p += BATCH * PCH * DIM * 4;   // 256 KB
    float* pcnt       = (float*)p; p += BATCH * PCH * 4;
    float* pm         = (float*)p; p += NROWS * CHUNKS * 4;
    float* ps         = (float*)p; p += NROWS * CHUNKS * 4;
    float* ptopv      = (float*)p; p += NROWS * CHUNKS * 8 * 4;
    int*   ptopi      = (int*)p;   p += NROWS * CHUNKS * 8 * 4;
    int*   alive_seq  = (int*)p;   p += NROWS * MAXLEN * 4;
    int*   fin_seq    = (int*)p;   p += NROWS * MAXLEN * 4;
    float* alive_lp   = (float*)p; p += NROWS * 4;
    float* fin_scores = (float*)p; p += NROWS * 4;
    int*   fin_flags  = (int*)p;   p += NROWS * 4;
    int*   batch_fin  = (int*)p;   p += BATCH * 4;

    k_pool2<<<dim3(BATCH, PCH), DIM, 0, stream>>>(src, Esrc, pp, pcnt);
    k_poolred<<<BATCH, DIM, 0, stream>>>(pp, pcnt, pooled);
    k_init<<<1, 1024, 0, stream>>>(alive_seq, alive_lp, fin_seq, fin_scores, fin_flags, batch_fin);
    for (int t = 0; t < MAXLEN - 1; ++t) {
        k_x<<<NROWS, DIM, 0, stream>>>(Etgt, pooled, alive_seq, t, xT);
        if (big8) {
            k_gemm8<DIM/8><<<dim3(VOCABSZ / 256, 1, 8), 256, 0, stream>>>(xT, W, partial);
            k_part<8><<<dim3(NROWS, CHUNKS), 1024, 0, stream>>>(partial, bias, pm, ps, ptopv, ptopi);
        } else if (big4) {
            k_gemm8<DIM/4><<<dim3(VOCABSZ / 256, 1, 4), 256, 0, stream>>>(xT, W, partial);
            k_part<4><<<dim3(NROWS, CHUNKS), 1024, 0, stream>>>(partial, bias, pm, ps, ptopv, ptopi);
        } else {
            k_gemm8<DIM/2><<<dim3(VOCABSZ / 256, 1, 2), 256, 0, stream>>>(xT, W, partial);
            k_part<2><<<dim3(NROWS, CHUNKS), 1024, 0, stream>>>(partial, bias, pm, ps, ptopv, ptopi);
        }
        k_mergesel<<<BATCH, 64, 0, stream>>>(pm, ps, ptopv, ptopi, alive_seq, alive_lp,
                                             fin_seq, fin_scores, fin_flags, batch_fin, t);
    }
    k_out<<<1, 256, 0, stream>>>(fin_seq, out);
}

// Round 7
// 1077.644 us; speedup vs baseline: 1.5511x; 1.0558x over previous
//
#include <hip/hip_runtime.h>
#include <math.h>

#define BATCH 16
#define SRCLEN 128
#define DIM 512
#define VOCABSZ 32000
#define BEAM 4
#define MAXLEN 16
#define NROWS (BATCH*BEAM)   // 64
#define BOS_TOK 1
#define EOS_TOK 2
#define NEGINF 1e9f
#define CHUNKS 8
#define CHUNK 4000           // VOCABSZ / CHUNKS
#define PCH 8                // pool s-chunks
#define PCL (SRCLEN/PCH)     // 16 s per chunk

// ---------------- key pack/unpack: (ordered float << 32) | (0xFFFFFFFF - id) ----------------
__device__ inline unsigned long long packkey(float v, int idx) {
    unsigned int fb = __float_as_uint(v);
    fb = fb ^ ((fb >> 31) ? 0xFFFFFFFFu : 0x80000000u);
    return ((unsigned long long)fb << 32) | (unsigned long long)(0xFFFFFFFFu - (unsigned int)idx);
}
__device__ inline float unpack_val(unsigned long long k) {
    unsigned int fb = (unsigned int)(k >> 32);
    fb = fb ^ ((fb >> 31) ? 0x80000000u : 0xFFFFFFFFu);
    return __uint_as_float(fb);
}
__device__ inline int unpack_id(unsigned long long k) {
    return (int)(0xFFFFFFFFu - (unsigned int)(k & 0xFFFFFFFFu));
}
__device__ inline unsigned long long shflxor64(unsigned long long x, int mask) {
    unsigned int lo = (unsigned int)x, hi = (unsigned int)(x >> 32);
    lo = (unsigned int)__shfl_xor((int)lo, mask, 64);
    hi = (unsigned int)__shfl_xor((int)hi, mask, 64);
    return ((unsigned long long)hi << 32) | (unsigned long long)lo;
}
__device__ inline unsigned long long wavemax64(unsigned long long k) {
#pragma unroll
    for (int off = 1; off < 64; off <<= 1) {
        unsigned long long o = shflxor64(k, off);
        k = (o > k) ? o : k;
    }
    return k;
}

// ---------------- encoder pool, phase 1: per-(b, s-chunk) partial sum + count ----------------
__global__ __launch_bounds__(512) void k_pool2(const int* __restrict__ src,
                                               const float* __restrict__ Esrc,
                                               float* __restrict__ pp, float* __restrict__ pcnt) {
    int b = blockIdx.x, c = blockIdx.y;
    int d = threadIdx.x;
    float acc = 0.f, cnt = 0.f;
#pragma unroll
    for (int s = 0; s < PCL; ++s) {
        int tok = src[b * SRCLEN + c * PCL + s];
        if (tok != 0) { acc += Esrc[(size_t)tok * DIM + d]; cnt += 1.f; }
    }
    pp[(b * PCH + c) * DIM + d] = acc;
    if (d == 0) pcnt[b * PCH + c] = cnt;
}

// ---------------- encoder pool, phase 2: reduce chunks (ascending, deterministic) ----------------
__global__ __launch_bounds__(512) void k_poolred(const float* __restrict__ pp,
                                                 const float* __restrict__ pcnt,
                                                 float* __restrict__ pooled) {
    int b = blockIdx.x;
    int d = threadIdx.x;
    float acc = 0.f, cnt = 0.f;
#pragma unroll
    for (int c = 0; c < PCH; ++c) { acc += pp[(b * PCH + c) * DIM + d]; cnt += pcnt[b * PCH + c]; }
    pooled[b * DIM + d] = acc / fmaxf(cnt, 1.f);
}

// ---------------- state init ----------------
__global__ __launch_bounds__(1024) void k_init(int* __restrict__ alive_seq, float* __restrict__ alive_lp,
                                               int* __restrict__ fin_seq, float* __restrict__ fin_scores,
                                               int* __restrict__ fin_flags, int* __restrict__ batch_fin) {
    int tid = threadIdx.x;  // 1024 = NROWS*MAXLEN
    alive_seq[tid] = (tid % MAXLEN == 0) ? BOS_TOK : 0;
    fin_seq[tid] = 0;
    if (tid < NROWS) {
        alive_lp[tid] = (tid % BEAM == 0) ? 0.f : -INFINITY;
        fin_scores[tid] = -NEGINF;
        fin_flags[tid] = 0;
    }
    if (tid < BATCH) batch_fin[tid] = 0;
}

// ---------------- decoder input, transposed: xT[d][i] = E_tgt[last_i][d] + pooled[i/4][d] ----------------
__global__ __launch_bounds__(512) void k_x(const float* __restrict__ Etgt,
                                           const float* __restrict__ pooled,
                                           const int* __restrict__ alive_seq, int t,
                                           float* __restrict__ xT) {
    int i = blockIdx.x;   // row 0..63
    int d = threadIdx.x;  // 0..511
    int last = alive_seq[i * MAXLEN + t];
    float v = Etgt[(size_t)last * DIM + d] + pooled[(i >> 2) * DIM + d];
    xT[d * NROWS + i] = v;
}

// ---------------- logits GEMM: 16r x 4v lane, W double-buffered 4-d chunks, x in LDS ----------------
// R12 post-mortem of R11 (k_gemm8): VALU 27% at ~2.2 waves/SIMD. Per d-step a
// wave has 128 FMA-cyc vs L3-latency ~500-700 cyc W loads; compiler unroll-2
// lookahead 256 cyc -> ~340 stall cyc per 128 busy. Fix: hand-pipelined 4-d
// chunks, W double-buffered in registers -- chunk B's 4 loads issue BEFORE
// chunk A's 512 FMA-cyc, and vice versa -> >=512-cyc cover per wave (x2
// waves/SIMD ~ 1024 > L3 latency). x staged once in 32KB LDS (no in-loop
// barriers; uniform ds_read_b128 broadcast, lgkm-scheduled by compiler).
// All buffers statically named (no runtime-indexed arrays -> no scratch).
// z=4 (GDLEN=128): 500 blocks ~2/CU; partial 32MB write (vs R6's 64).
// Per-slab d-ascending accumulation, FMA order per (row,v) identical to
// gemm8 -> same reassociation class; k_part<4> verified absmax=0 (R1/R5).
#define FMA4(i, xs, wq) \
    acc[i].x = fmaf((xs),(wq).x,acc[i].x); acc[i].y = fmaf((xs),(wq).y,acc[i].y); \
    acc[i].z = fmaf((xs),(wq).z,acc[i].z); acc[i].w = fmaf((xs),(wq).w,acc[i].w);
#define FMAD_LDS(wq, dd) { \
    float4 xa = *(const float4*)(xsp + (dd) * NROWS);      \
    float4 xb = *(const float4*)(xsp + (dd) * NROWS + 4);  \
    float4 xc = *(const float4*)(xsp + (dd) * NROWS + 8);  \
    float4 xd = *(const float4*)(xsp + (dd) * NROWS + 12); \
    FMA4(0, xa.x, wq)  FMA4(1, xa.y, wq)  FMA4(2, xa.z, wq)  FMA4(3, xa.w, wq)  \
    FMA4(4, xb.x, wq)  FMA4(5, xb.y, wq)  FMA4(6, xb.z, wq)  FMA4(7, xb.w, wq)  \
    FMA4(8, xc.x, wq)  FMA4(9, xc.y, wq)  FMA4(10, xc.z, wq) FMA4(11, xc.w, wq) \
    FMA4(12, xd.x, wq) FMA4(13, xd.y, wq) FMA4(14, xd.z, wq) FMA4(15, xd.w, wq) }
#define LOADW(P, dbase) \
    w##P##0 = *(const float4*)(wp + (size_t)((dbase)+0) * VOCABSZ); \
    w##P##1 = *(const float4*)(wp + (size_t)((dbase)+1) * VOCABSZ); \
    w##P##2 = *(const float4*)(wp + (size_t)((dbase)+2) * VOCABSZ); \
    w##P##3 = *(const float4*)(wp + (size_t)((dbase)+3) * VOCABSZ);
#define FMACHUNK(P, dbase) \
    FMAD_LDS(w##P##0, (dbase)+0) FMAD_LDS(w##P##1, (dbase)+1) \
    FMAD_LDS(w##P##2, (dbase)+2) FMAD_LDS(w##P##3, (dbase)+3)

template<int GDLEN>
__global__ __launch_bounds__(256) void k_gemm9(const float* __restrict__ xT,
                                               const float* __restrict__ W,
                                               float* __restrict__ partial) {
    int lane = threadIdx.x & 63;
    int r0 = __builtin_amdgcn_readfirstlane((threadIdx.x >> 6) * 16);  // wave-uniform
    int v0 = blockIdx.x * 256 + lane * 4;
    int z  = blockIdx.z;
    int d0 = z * GDLEN;

    __shared__ float xs[GDLEN * NROWS];     // 32 KB at GDLEN=128
    {
        const float4* xg = (const float4*)(xT + (size_t)d0 * NROWS);
        float4* xs4 = (float4*)xs;
#pragma unroll
        for (int i = 0; i < (GDLEN * NROWS / 4) / 256; ++i)
            xs4[i * 256 + threadIdx.x] = xg[i * 256 + threadIdx.x];
    }
    __syncthreads();

    float4 acc[16];
#pragma unroll
    for (int i = 0; i < 16; ++i) acc[i] = make_float4(0.f, 0.f, 0.f, 0.f);

    const float* wp  = W + (size_t)d0 * VOCABSZ + v0;
    const float* xsp = xs + r0;
    float4 wA0, wA1, wA2, wA3, wB0, wB1, wB2, wB3;

    const int nc = GDLEN / 4;               // chunks of 4 d-steps; nc even
    LOADW(A, 0)
    for (int c = 0; c < nc; c += 2) {
        LOADW(B, (c + 1) * 4)               // prefetch B before A's FMAs
        FMACHUNK(A, c * 4)
        if (c + 2 < nc) { LOADW(A, (c + 2) * 4) }  // prefetch next A before B's FMAs
        FMACHUNK(B, (c + 1) * 4)
    }

    float* op = partial + (size_t)z * NROWS * VOCABSZ + (size_t)r0 * VOCABSZ + v0;
#pragma unroll
    for (int r = 0; r < 16; ++r)
        *(float4*)(op + (size_t)r * VOCABSZ) = acc[r];
}

// ---------------- per-(row,chunk): partial max, sumexp, top-8 ----------------
// R8: 1024 threads (32 waves/CU), 1 float4/slab per thread (all loads
// independent/in-flight), 4-barrier merge: sort-4 network -> per-wave top-8
// via shfl wave-max rounds -> 128 keys in LDS -> wave0 extracts block top-8.
template<int NZ>
__global__ __launch_bounds__(1024) void k_part(const float* __restrict__ partial,
                                               const float* __restrict__ bias,
                                               float* __restrict__ pm, float* __restrict__ ps,
                                               float* __restrict__ ptopv, int* __restrict__ ptopi) {
    int row = blockIdx.x, ch = blockIdx.y;
    int tid = threadIdx.x;
    int lane = tid & 63;
    int wv = tid >> 6;                    // 0..15
    const size_t slab = (size_t)NROWS * VOCABSZ;
    const bool valid = tid < (CHUNK / 4); // 1000 float4 positions

    float vals[4] = {-INFINITY, -INFINITY, -INFINITY, -INFINITY};
    if (valid) {
        const float4* l0 = (const float4*)(partial + (size_t)row * VOCABSZ + ch * CHUNK);
        float4 q = l0[tid];
#pragma unroll
        for (int zz = 1; zz < NZ; ++zz) {
            const float4* lz = (const float4*)(partial + slab * zz + (size_t)row * VOCABSZ + ch * CHUNK);
            float4 q2 = lz[tid];
            q.x += q2.x; q.y += q2.y; q.z += q2.z; q.w += q2.w;
        }
        float4 bb = ((const float4*)(bias + ch * CHUNK))[tid];
        vals[0] = q.x + bb.x; vals[1] = q.y + bb.y; vals[2] = q.z + bb.z; vals[3] = q.w + bb.w;
    }

    // ---- block max: wave butterfly + 16-entry LDS combine ----
    float m_t = fmaxf(fmaxf(vals[0], vals[1]), fmaxf(vals[2], vals[3]));
#pragma unroll
    for (int off = 1; off < 64; off <<= 1) m_t = fmaxf(m_t, __shfl_xor(m_t, off, 64));
    __shared__ float swred[16];
    if (lane == 0) swred[wv] = m_t;
    __syncthreads();
    float m = swred[0];
#pragma unroll
    for (int w = 1; w < 16; ++w) m = fmaxf(m, swred[w]);
    __syncthreads();   // swred reused for sums below

    // ---- block sumexp ----
    float se = 0.f;
    if (valid) {
#pragma unroll
        for (int c = 0; c < 4; ++c) se += expf(vals[c] - m);
    }
#pragma unroll
    for (int off = 1; off < 64; off <<= 1) se += __shfl_xor(se, off, 64);
    if (lane == 0) swred[wv] = se;
    __syncthreads();
    if (tid == 0) {
        float s = 0.f;
#pragma unroll
        for (int w = 0; w < 16; ++w) s += swred[w];
        pm[row * CHUNKS + ch] = m;
        ps[row * CHUNKS + ch] = s;
    }

    // ---- top-8: per-lane sort-4 -> per-wave 8 rounds wave-max -> 128-key final ----
    int gi = ch * CHUNK + tid * 4;
    unsigned long long k0 = 0ULL, k1 = 0ULL, k2 = 0ULL, k3 = 0ULL;
    if (valid) {   // keys never 0 for real values (idx < 2^31) -> 0 is a safe sentinel
        k0 = packkey(vals[0], gi);
        k1 = packkey(vals[1], gi + 1);
        k2 = packkey(vals[2], gi + 2);
        k3 = packkey(vals[3], gi + 3);
    }
    {
        unsigned long long tswp;
#define CSW(a,b) if (b > a) { tswp = a; a = b; b = tswp; }
        CSW(k0,k1) CSW(k2,k3) CSW(k0,k2) CSW(k1,k3) CSW(k1,k2)
#undef CSW
    }
    __shared__ unsigned long long skey[128];
    {
        int pos = 0;
        unsigned long long wtop[8];
#pragma unroll
        for (int r = 0; r < 8; ++r) {
            unsigned long long head = (pos == 0) ? k0 : (pos == 1) ? k1 :
                                      (pos == 2) ? k2 : (pos == 3) ? k3 : 0ULL;
            unsigned long long mx = wavemax64(head);
            if (head == mx && head != 0ULL) pos++;   // unique keys -> exactly one winner
            wtop[r] = mx;
        }
        if (lane == 0) {
#pragma unroll
            for (int r = 0; r < 8; ++r) skey[wv * 8 + r] = wtop[r];
        }
    }
    __syncthreads();
    if (tid < 64) {   // wave 0 exactly; no barriers below
        unsigned long long a = skey[tid];
        unsigned long long b2 = skey[64 + tid];
        unsigned long long hi = (a > b2) ? a : b2;
        unsigned long long lo = (a > b2) ? b2 : a;
        float* otv = ptopv + ((size_t)row * CHUNKS + ch) * 8;
        int*   oti = ptopi + ((size_t)row * CHUNKS + ch) * 8;
        int pos = 0;
#pragma unroll
        for (int r = 0; r < 8; ++r) {
            unsigned long long head = (pos == 0) ? hi : (pos == 1) ? lo : 0ULL;
            unsigned long long mx = wavemax64(head);
            if (head == mx && head != 0ULL) pos++;
            if (tid == 0) { otv[r] = unpack_val(mx); oti[r] = unpack_id(mx); }
        }
    }
}

// ---------------- merge + beam bookkeeping, one block (one wave) per batch ----------------
__global__ __launch_bounds__(64) void k_mergesel(const float* __restrict__ pm, const float* __restrict__ ps,
                                                 const float* __restrict__ ptopv, const int* __restrict__ ptopi,
                                                 int* __restrict__ alive_seq, float* __restrict__ alive_lp,
                                                 int* __restrict__ fin_seq, float* __restrict__ fin_scores,
                                                 int* __restrict__ fin_flags, int* __restrict__ batch_fin, int t) {
    int b = blockIdx.x;
    int tid = threadIdx.x;
    __shared__ int aseq_old[BEAM][MAXLEN]; __shared__ int fseq_old[BEAM][MAXLEN];
    __shared__ float s_tlp[8]; __shared__ int s_ttok[8], s_tbeam[8];
    __shared__ int s_aidx[4], s_fidx[4];
    __shared__ float s_nfsc[4]; __shared__ int s_nffl[4];
    float lpen = (float)(t + 1);

    { int k = tid >> 4, p = tid & 15;
      aseq_old[k][p] = alive_seq[(b * BEAM + k) * MAXLEN + p];
      fseq_old[k][p] = fin_seq[(b * BEAM + k) * MAXLEN + p]; }

    float rv[4]; int ri[4];
#pragma unroll
    for (int k = 0; k < 4; ++k) {
        rv[k] = ptopv[(size_t)(b * BEAM + k) * 64 + tid];
        ri[k] = ptopi[(size_t)(b * BEAM + k) * 64 + tid];
    }

    float alp[4], fsc[4]; int ffl[4];
#pragma unroll
    for (int k = 0; k < 4; ++k) {
        alp[k] = alive_lp[b * BEAM + k];
        fsc[k] = fin_scores[b * BEAM + k];
        ffl[k] = fin_flags[b * BEAM + k];
    }
    int bf_old = batch_fin[b];

    float srm[4], srl[4];
#pragma unroll
    for (int k = 0; k < 4; ++k) {
        float m = -INFINITY;
#pragma unroll
        for (int c = 0; c < CHUNKS; ++c) m = fmaxf(m, pm[(b * BEAM + k) * CHUNKS + c]);
        float s = 0.f;
#pragma unroll
        for (int c = 0; c < CHUNKS; ++c) s += ps[(b * BEAM + k) * CHUNKS + c] * expf(pm[(b * BEAM + k) * CHUNKS + c] - m);
        srm[k] = m; srl[k] = logf(s);
    }

    unsigned long long key[4];
#pragma unroll
    for (int k = 0; k < 4; ++k) {
        float sh = rv[k] - srm[k];
        float lp = sh - srl[k];
        float full = alp[k] + lp;
        float cv = full / lpen;
        key[k] = packkey(cv, k * VOCABSZ + ri[k]);
    }
    {
        unsigned long long tmp;
#define CSW(a,b) if (key[b] > key[a]) { tmp = key[a]; key[a] = key[b]; key[b] = tmp; }
        CSW(0,1) CSW(2,3) CSW(0,2) CSW(1,3) CSW(1,2)
#undef CSW
    }

    float tscore[8], tlp[8]; int ttok[8], tbeam[8], tfin[8];
    int pos = 0;
#pragma unroll
    for (int r = 0; r < 8; ++r) {
        unsigned long long head = (pos == 0) ? key[0] : (pos == 1) ? key[1] :
                                  (pos == 2) ? key[2] : (pos == 3) ? key[3] : 0ULL;
        unsigned long long mx = wavemax64(head);
        if (head == mx && head != 0ULL) pos++;
        float sc = unpack_val(mx);
        int id = unpack_id(mx);
        tscore[r] = sc;
        tlp[r] = sc * lpen;
        ttok[r] = id % VOCABSZ;
        tbeam[r] = id / VOCABSZ;
        tfin[r] = (ttok[r] == EOS_TOK) ? 1 : 0;
    }

    int aidx[4];
    {
        float curr[8];
#pragma unroll
        for (int j = 0; j < 8; ++j) curr[j] = tscore[j] + (tfin[j] ? -NEGINF : 0.0f);
        unsigned int used = 0;
#pragma unroll
        for (int r = 0; r < 4; ++r) {
            float bv = 0.f; int bj = -1;
#pragma unroll
            for (int j = 0; j < 8; ++j) {
                bool skip = (used >> j) & 1u;
                bool better = !skip && (bj < 0 || curr[j] > bv);
                if (better) { bv = curr[j]; bj = j; }
            }
            used |= 1u << bj; aidx[r] = bj;
        }
    }
    int fidx[4]; float nfsc[4]; int nffl[4];
    {
        float fscand[12]; int fflcand[12];
#pragma unroll
        for (int j = 0; j < 4; ++j) { fscand[j] = fsc[j]; fflcand[j] = ffl[j]; }
#pragma unroll
        for (int q = 0; q < 8; ++q) {
            float t1 = tscore[q] + (tfin[q] ? 0.0f : -NEGINF);
            float t2 = t1 + (bf_old ? -NEGINF : 0.0f);
            fscand[4 + q] = t2; fflcand[4 + q] = tfin[q];
        }
        unsigned int used = 0;
#pragma unroll
        for (int r = 0; r < 4; ++r) {
            float bv = 0.f; int bj = -1;
#pragma unroll
            for (int j = 0; j < 12; ++j) {
                bool skip = (used >> j) & 1u;
                bool better = !skip && (bj < 0 || fscand[j] > bv);
                if (better) { bv = fscand[j]; bj = j; }
            }
            used |= 1u << bj; fidx[r] = bj;
            nfsc[r] = bv;
        }
#pragma unroll
        for (int r = 0; r < 4; ++r) {
            int bj = fidx[r]; int fl = 0;
#pragma unroll
            for (int j = 0; j < 12; ++j) if (bj == j) fl = fflcand[j];
            nffl[r] = fl;
        }
    }

    if (tid == 0) {
#pragma unroll
        for (int r = 0; r < 8; ++r) { s_tlp[r] = tlp[r]; s_ttok[r] = ttok[r]; s_tbeam[r] = tbeam[r]; }
#pragma unroll
        for (int r = 0; r < 4; ++r) { s_aidx[r] = aidx[r]; s_fidx[r] = fidx[r]; s_nfsc[r] = nfsc[r]; s_nffl[r] = nffl[r]; }
    }
    __syncthreads();

    { int k = tid >> 4, p = tid & 15;
      int j = s_aidx[k];
      int val = (p == t + 1) ? s_ttok[j] : aseq_old[s_tbeam[j]][p];
      alive_seq[(b * BEAM + k) * MAXLEN + p] = val;
      int fi = s_fidx[k]; int fval;
      if (fi < 4) fval = fseq_old[fi][p];
      else { int q = fi - 4; fval = (p == t + 1) ? s_ttok[q] : aseq_old[s_tbeam[q]][p]; }
      fin_seq[(b * BEAM + k) * MAXLEN + p] = fval; }

    if (tid < 4) {
        alive_lp[b * BEAM + tid] = s_tlp[s_aidx[tid]];
        fin_scores[b * BEAM + tid] = s_nfsc[tid];
        fin_flags[b * BEAM + tid] = s_nffl[tid];
    }
    if (tid == 0) {
        float lb = s_tlp[s_aidx[0]] / lpen;
        float lowest = nfsc[0] * (nffl[0] ? 1.f : 0.f);
        int allf = nffl[0];
#pragma unroll
        for (int k2 = 1; k2 < 4; ++k2) {
            float pz = nfsc[k2] * (nffl[k2] ? 1.f : 0.f);
            lowest = fminf(lowest, pz);
            allf = allf && nffl[k2];
        }
        lowest = lowest + (allf ? 0.f : -NEGINF);
        batch_fin[b] = bf_old || (lowest >= lb);
    }
}

// ---------------- output: fin_seq[:,0,:] as float ----------------
__global__ __launch_bounds__(256) void k_out(const int* __restrict__ fin_seq, float* __restrict__ out) {
    int tid = threadIdx.x;
    if (tid < BATCH * MAXLEN) {
        int b = tid / MAXLEN, p = tid % MAXLEN;
        out[tid] = (float)fin_seq[(b * BEAM + 0) * MAXLEN + p];
    }
}

extern "C" void kernel_launch(void* const* d_in, const int* in_sizes, int n_in,
                              void* d_out, int out_size, void* d_ws, size_t ws_size,
                              hipStream_t stream) {
    const int*   src  = (const int*)d_in[0];
    const float* Esrc = (const float*)d_in[1];
    const float* Etgt = (const float*)d_in[2];
    const float* W    = (const float*)d_in[3];
    const float* bias = (const float*)d_in[4];
    float* out = (float*)d_out;

    const size_t slab = (size_t)NROWS * VOCABSZ * 4;  // 8.192 MB
    const bool big4 = ws_size >= 4 * slab + (2u << 20);
    const int NZ = big4 ? 4 : 2;

    char* p = (char*)d_ws;
    float* partial    = (float*)p; p += NZ * slab;
    float* pooled     = (float*)p; p += BATCH * DIM * 4;
    float* xT         = (float*)p; p += DIM * NROWS * 4;
    float* pp         = (float*)p; p += BATCH * PCH * DIM * 4;   // 256 KB
    float* pcnt       = (float*)p; p += BATCH * PCH * 4;
    float* pm         = (float*)p; p += NROWS * CHUNKS * 4;
    float* ps         = (float*)p; p += NROWS * CHUNKS * 4;
    float* ptopv      = (float*)p; p += NROWS * CHUNKS * 8 * 4;
    int*   ptopi      = (int*)p;   p += NROWS * CHUNKS * 8 * 4;
    int*   alive_seq  = (int*)p;   p += NROWS * MAXLEN * 4;
    int*   fin_seq    = (int*)p;   p += NROWS * MAXLEN * 4;
    float* alive_lp   = (float*)p; p += NROWS * 4;
    float* fin_scores = (float*)p; p += NROWS * 4;
    int*   fin_flags  = (int*)p;   p += NROWS * 4;
    int*   batch_fin  = (int*)p;   p += BATCH * 4;

    k_pool2<<<dim3(BATCH, PCH), DIM, 0, stream>>>(src, Esrc, pp, pcnt);
    k_poolred<<<BATCH, DIM, 0, stream>>>(pp, pcnt, pooled);
    k_init<<<1, 1024, 0, stream>>>(alive_seq, alive_lp, fin_seq, fin_scores, fin_flags, batch_fin);
    for (int t = 0; t < MAXLEN - 1; ++t) {
        k_x<<<NROWS, DIM, 0, stream>>>(Etgt, pooled, alive_seq, t, xT);
        if (big4) {
            k_gemm9<DIM/4><<<dim3(VOCABSZ / 256, 1, 4), 256, 0, stream>>>(xT, W, partial);
            k_part<4><<<dim3(NROWS, CHUNKS), 1024, 0, stream>>>(partial, bias, pm, ps, ptopv, ptopi);
        } else {
            k_gemm9<DIM/2><<<dim3(VOCABSZ / 256, 1, 2), 256, 0, stream>>>(xT, W, partial);
            k_part<2><<<dim3(NROWS, CHUNKS), 1024, 0, stream>>>(partial, bias, pm, ps, ptopv, ptopi);
        }
        k_mergesel<<<BATCH, 64, 0, stream>>>(pm, ps, ptopv, ptopi, alive_seq, alive_lp,
                                             fin_seq, fin_scores, fin_flags, batch_fin, t);
    }
    k_out<<<1, 256, 0, stream>>>(fin_seq, out);
}